// Round 14
// baseline (250.560 us; speedup 1.0000x reference)
//
#include <hip/hip_runtime.h>
#include <cstddef>
#include <cstdint>

#define B_ 4
#define N_ 16384
#define M_ 2048
#define C_ 128
#define NQ (B_*M_)         // 8192 queries
#define NSAMP 32
#define SAMP (NQ*NSAMP)    // 262144 samples
#define EPS_ 1e-5f
#define R2_ 9.0f

typedef short s8v  __attribute__((ext_vector_type(8)));
typedef short s4v  __attribute__((ext_vector_type(4)));
typedef float f32x4 __attribute__((ext_vector_type(4)));

// stats: 8 contention-split copies of a 1024-float block
#define ST_COPIES 8
#define ST_S0S 0
#define ST_S0Q 64
#define ST_S1S 128
#define ST_S1Q 136
#define ST_M1S 144
#define ST_M1Q 272
#define ST_M2S 400
#define ST_M2Q 656

__device__ __forceinline__ unsigned short f2bf(float f) {
    unsigned int u = __builtin_bit_cast(unsigned int, f);
    u += 0x7fffu + ((u >> 16) & 1u);     // round-to-nearest-even
    return (unsigned short)(u >> 16);
}
__device__ __forceinline__ float bf2f(unsigned short h) {
    unsigned int u = ((unsigned int)h) << 16;
    return __builtin_bit_cast(float, u);
}

// ---- prep: reorder+pad mlp_w0 (128x131 -> 128x160 bf16, feat-first), cast mlp_w1 (256x128 bf16)
__global__ void k_prep_w(const float* __restrict__ w0, const float* __restrict__ w1,
                         unsigned short* __restrict__ w0p, unsigned short* __restrict__ w1p) {
    int i = blockIdx.x * 256 + threadIdx.x;
    const int tot0 = 128 * 160;
    if (i < tot0) {
        int o = i / 160, c = i - o * 160;
        float v = 0.f;
        if (c < 128)      v = w0[o * 131 + 3 + c];
        else if (c < 131) v = w0[o * 131 + (c - 128)];
        w0p[i] = f2bf(v);
    }
    int j = i - tot0;
    if (j >= 0 && j < 256 * 128) w1p[j] = f2bf(w1[j]);
}

// ---- transpose backbone_features (B,C,N) f32 -> featT (B,N,C) bf16; vectorized write side
__global__ void k_transpose(const float* __restrict__ feat, unsigned short* __restrict__ featT) {
    __shared__ unsigned short tl[64][130];
    int b  = blockIdx.x >> 8;
    int n0 = (blockIdx.x & 255) * 64;
    const float* src = feat + (size_t)b * C_ * N_;
    int t = threadIdx.x;
    for (int i = 0; i < 32; ++i) {
        int lin = i * 256 + t;
        int c = lin >> 6, n = lin & 63;
        tl[n][c] = f2bf(src[(size_t)c * N_ + n0 + n]);
    }
    __syncthreads();
    unsigned short* dst = featT + ((size_t)b * N_ + n0) * 128;
    #pragma unroll
    for (int i = 0; i < 4; ++i) {
        int lin = i * 256 + t;
        int n = lin >> 4, cg = lin & 15;
        s8v v;
        #pragma unroll
        for (int e = 0; e < 8; ++e) v[e] = (short)tl[n][cg*8 + e];
        *(s8v*)(dst + (size_t)n * 128 + cg * 8) = v;
    }
}

// ---- shift MLP layer 0
__global__ void k_shift0(const float* __restrict__ xyz, const float* __restrict__ w0s,
                         float* __restrict__ t0, float* __restrict__ stats) {
    __shared__ float w[192];
    __shared__ float ps[4][64], pq[4][64];
    int t = threadIdx.x, wave = t >> 6, lane = t & 63;
    if (t < 192) w[t] = w0s[t];
    __syncthreads();
    int p = blockIdx.x * 256 + t;
    float q0 = xyz[p*3], q1 = xyz[p*3+1], q2 = xyz[p*3+2];
    float* orow = t0 + (size_t)p * 64;
    #pragma unroll
    for (int o = 0; o < 64; ++o) {
        float v = w[3*o]*q0 + w[3*o+1]*q1 + w[3*o+2]*q2;
        orow[o] = v;
        float s = v, sq = v * v;
        #pragma unroll
        for (int mk = 32; mk; mk >>= 1) { s += __shfl_xor(s, mk); sq += __shfl_xor(sq, mk); }
        if (lane == 0) { ps[wave][o] = s; pq[wave][o] = sq; }
    }
    __syncthreads();
    if (t < 64) {
        float s = ps[0][t] + ps[1][t] + ps[2][t] + ps[3][t];
        float q = pq[0][t] + pq[1][t] + pq[2][t] + pq[3][t];
        atomicAdd(&stats[ST_S0S + t], s);
        atomicAdd(&stats[ST_S0Q + t], q);
    }
}

// ---- shift layer 1
__global__ void k_shift1(const float* __restrict__ t0, const float* __restrict__ w1s,
                         const float* __restrict__ g0, const float* __restrict__ b0,
                         float* __restrict__ t1, float* __restrict__ stats) {
    __shared__ float aa[64], bb[64], wl[192];
    __shared__ float ps[4][3], pq[4][3];
    int t = threadIdx.x, wave = t >> 6, lane = t & 63;
    if (t < 64) {
        float mean = stats[ST_S0S + t] * (1.f / NQ);
        float var  = stats[ST_S0Q + t] * (1.f / NQ) - mean * mean;
        float a = g0[t] * rsqrtf(var + EPS_);
        aa[t] = a; bb[t] = b0[t] - mean * a;
    }
    if (t < 192) wl[t] = w1s[t];
    __syncthreads();
    int p = blockIdx.x * 256 + t;
    const f32x4* xr = (const f32x4*)(t0 + (size_t)p * 64);
    float v0 = 0.f, v1 = 0.f, v2 = 0.f;
    #pragma unroll
    for (int i = 0; i < 16; ++i) {
        f32x4 x = xr[i];
        #pragma unroll
        for (int j = 0; j < 4; ++j) {
            int c = 4*i + j;
            float h = fmaxf(0.f, aa[c] * x[j] + bb[c]);
            v0 += wl[c] * h; v1 += wl[64 + c] * h; v2 += wl[128 + c] * h;
        }
    }
    t1[p*3] = v0; t1[p*3+1] = v1; t1[p*3+2] = v2;
    float vv[3] = {v0, v1, v2};
    #pragma unroll
    for (int o = 0; o < 3; ++o) {
        float s = vv[o], q = vv[o] * vv[o];
        #pragma unroll
        for (int mk = 32; mk; mk >>= 1) { s += __shfl_xor(s, mk); q += __shfl_xor(q, mk); }
        if (lane == 0) { ps[wave][o] = s; pq[wave][o] = q; }
    }
    __syncthreads();
    if (t < 3) {
        float s = ps[0][t] + ps[1][t] + ps[2][t] + ps[3][t];
        float q = pq[0][t] + pq[1][t] + pq[2][t] + pq[3][t];
        atomicAdd(&stats[ST_S1S + t], s);
        atomicAdd(&stats[ST_S1Q + t], q);
    }
}

// ---- shift output
__global__ void k_shift2(const float* __restrict__ t1, const float* __restrict__ g1,
                         const float* __restrict__ b1, const float* __restrict__ stats,
                         float* __restrict__ nxyz) {
    int p = blockIdx.x * 256 + threadIdx.x;
    for (int o = 0; o < 3; ++o) {
        float mean = stats[ST_S1S + o] * (1.f / NQ);
        float var  = stats[ST_S1Q + o] * (1.f / NQ) - mean * mean;
        float a = g1[o] * rsqrtf(var + EPS_);
        float bbv = b1[o] - mean * a;
        nxyz[p*3+o] = fmaxf(0.f, a * t1[p*3+o] + bbv);
    }
}

// ---- ball query v3: LDS-chunked scan. 128 blocks, 64 queries/block (one batch each),
// bxyz staged through LDS in 4 x 4096-point chunks; each wave serially scans its 16
// queries against the chunk (ds_read ~6cy vs L2 ~200cy). Ordered-first-32 semantics
// preserved exactly (chunks processed in index order, same _rn arithmetic).
__global__ void __launch_bounds__(256)
k_ballq(const float* __restrict__ bxyz, const float* __restrict__ nxyz,
        int* __restrict__ idxb) {
    __shared__ float pts[4096 * 3];          // 48 KB
    int tid = threadIdx.x, wave = tid >> 6, lane = tid & 63;
    int b = blockIdx.x >> 5;                 // 32 blocks per batch
    int qbase = blockIdx.x * 64 + wave * 16; // 16 queries per wave
    const float* bp = bxyz + (size_t)b * N_ * 3;
    unsigned long long below = (lane == 63) ? ~0ull >> 1 : ((1ull << lane) - 1ull);

    float qx[16], qy[16], qz[16], sq[16];
    int cnt[16], first[16];
    #pragma unroll
    for (int q = 0; q < 16; ++q) {
        qx[q] = nxyz[(qbase+q)*3]; qy[q] = nxyz[(qbase+q)*3+1]; qz[q] = nxyz[(qbase+q)*3+2];
        sq[q] = __fadd_rn(__fadd_rn(__fmul_rn(qx[q],qx[q]), __fmul_rn(qy[q],qy[q])), __fmul_rn(qz[q],qz[q]));
        cnt[q] = 0; first[q] = 0;
    }

    for (int ch = 0; ch < 4; ++ch) {
        __syncthreads();                     // everyone done reading previous chunk
        {   // load 4096 points (12288 floats) cooperatively, float4-vectorized
            const f32x4* src = (const f32x4*)(bp + ch * 12288);
            f32x4* d4 = (f32x4*)pts;
            #pragma unroll
            for (int i = 0; i < 12; ++i) d4[i*256 + tid] = src[i*256 + tid];
        }
        __syncthreads();
        #pragma unroll
        for (int q = 0; q < 16; ++q) {
            if (cnt[q] >= 32) continue;
            for (int j0 = 0; j0 < 4096 && cnt[q] < 32; j0 += 256) {
                #pragma unroll
                for (int u = 0; u < 4; ++u) {
                    if (cnt[q] < 32) {
                        int jl = j0 + u*64 + lane;
                        float x = pts[jl*3], y = pts[jl*3+1], z = pts[jl*3+2];
                        float sx  = __fadd_rn(__fadd_rn(__fmul_rn(x,x), __fmul_rn(y,y)), __fmul_rn(z,z));
                        float dot = __fadd_rn(__fadd_rn(__fmul_rn(qx[q],x), __fmul_rn(qy[q],y)), __fmul_rn(qz[q],z));
                        float d2  = __fsub_rn(__fadd_rn(sq[q], sx), __fmul_rn(2.0f, dot));
                        unsigned long long m = __ballot(d2 < R2_);
                        if (cnt[q] == 0 && m != 0ull)
                            first[q] = ch*4096 + j0 + u*64 + __ffsll((long long)m) - 1;
                        int pre = cnt[q] + __popcll(m & below);
                        if (((m >> lane) & 1ull) && pre < 32)
                            idxb[(size_t)(qbase+q)*32 + pre] = ch*4096 + jl;
                        cnt[q] += __popcll(m);
                    }
                }
            }
        }
    }
    #pragma unroll
    for (int q = 0; q < 16; ++q) {
        if (cnt[q] < 32) {
            int f = (cnt[q] == 0) ? 0 : first[q];
            for (int k = cnt[q] + lane; k < 32; k += 64) idxb[(size_t)(qbase+q)*32 + k] = f;
        }
    }
}

// ---- GEMM1 (QPB=8, grid 1024): FLIPPED, LDS-staged, 2 queries/round, register prefetch.
// Stats atomics go to the block's contention-split stats copy.
__global__ void __launch_bounds__(256)
k_gemm1(const unsigned short* __restrict__ featT, const float* __restrict__ bxyz,
        const float* __restrict__ nxyz, const int* __restrict__ idxb,
        const unsigned short* __restrict__ w0p, unsigned short* __restrict__ y1,
        float* __restrict__ stats) {
    __shared__ unsigned short gt[64][168];   // 64 samples x 160ch (+pad)
    __shared__ int pidx[256];
    __shared__ float nq[8][3];
    int tid  = threadIdx.x;
    int wave = tid >> 6, lane = tid & 63, quad = lane >> 4, l16 = lane & 15;
    int s2 = tid >> 2, part4 = tid & 3;
    int b = blockIdx.x >> 8;
    float* stc = stats + (size_t)(blockIdx.x & (ST_COPIES-1)) * 1024;

    s8v bfr[2][5];
    #pragma unroll
    for (int g = 0; g < 2; ++g)
        #pragma unroll
        for (int kk = 0; kk < 5; ++kk)
            bfr[g][kk] = *(const s8v*)(w0p + (wave*32 + g*16 + l16)*160 + kk*32 + quad*8);

    pidx[tid] = idxb[blockIdx.x * 256 + tid];
    if (tid < 24) nq[tid / 3][tid % 3] = nxyz[blockIdx.x * 24 + tid];
    if (tid < 64)
        for (int c = 131; c < 160; ++c) gt[tid][c] = 0;
    __syncthreads();

    s8v pv[4]; float prel0 = 0.f, prel1 = 0.f, prel2 = 0.f;
    {
        int pp = pidx[s2];
        const unsigned short* src = featT + ((size_t)(b * N_ + pp)) * 128 + part4 * 32;
        pv[0] = *(const s8v*)src;        pv[1] = *(const s8v*)(src + 8);
        pv[2] = *(const s8v*)(src + 16); pv[3] = *(const s8v*)(src + 24);
        if (tid < 64) {
            int pq_ = pidx[tid];
            const float* bx = bxyz + (size_t)(b * N_ + pq_) * 3;
            int q = tid >> 5;
            prel0 = bx[0] - nq[q][0]; prel1 = bx[1] - nq[q][1]; prel2 = bx[2] - nq[q][2];
        }
    }
    float csum[2] = {}, csq[2] = {};

    for (int r = 0; r < 4; ++r) {
        __syncthreads();
        *(s8v*)&gt[s2][part4*32]      = pv[0];
        *(s8v*)&gt[s2][part4*32 + 8]  = pv[1];
        *(s8v*)&gt[s2][part4*32 + 16] = pv[2];
        *(s8v*)&gt[s2][part4*32 + 24] = pv[3];
        if (tid < 64) {
            gt[tid][128] = f2bf(prel0); gt[tid][129] = f2bf(prel1); gt[tid][130] = f2bf(prel2);
        }
        if (r + 1 < 4) {
            int pp = pidx[(r+1)*64 + s2];
            const unsigned short* src = featT + ((size_t)(b * N_ + pp)) * 128 + part4 * 32;
            pv[0] = *(const s8v*)src;        pv[1] = *(const s8v*)(src + 8);
            pv[2] = *(const s8v*)(src + 16); pv[3] = *(const s8v*)(src + 24);
            if (tid < 64) {
                int pq_ = pidx[(r+1)*64 + tid];
                const float* bx = bxyz + (size_t)(b * N_ + pq_) * 3;
                int q = (r+1)*2 + (tid >> 5);
                prel0 = bx[0] - nq[q][0]; prel1 = bx[1] - nq[q][1]; prel2 = bx[2] - nq[q][2];
            }
        }
        __syncthreads();
        f32x4 acc[2][4] = {};
        #pragma unroll
        for (int kk = 0; kk < 5; ++kk) {
            s8v at[4];
            #pragma unroll
            for (int t = 0; t < 4; ++t)
                at[t] = *(const s8v*)&gt[t*16 + l16][kk*32 + quad*8];
            #pragma unroll
            for (int g = 0; g < 2; ++g)
                #pragma unroll
                for (int t = 0; t < 4; ++t)
                    acc[g][t] = __builtin_amdgcn_mfma_f32_16x16x32_bf16(at[t], bfr[g][kk], acc[g][t], 0, 0, 0);
        }
        size_t sbase = (size_t)blockIdx.x * 256 + r * 64;
        #pragma unroll
        for (int g = 0; g < 2; ++g) {
            int ch = wave*32 + g*16 + l16;
            #pragma unroll
            for (int t = 0; t < 4; ++t)
                #pragma unroll
                for (int rr = 0; rr < 4; ++rr) {
                    float v = acc[g][t][rr];
                    y1[(sbase + t*16 + quad*4 + rr) * 128 + ch] = f2bf(v);
                    csum[g] += v; csq[g] += v * v;
                }
        }
    }
    #pragma unroll
    for (int g = 0; g < 2; ++g) {
        float s = csum[g], q = csq[g];
        s += __shfl_xor(s, 16); s += __shfl_xor(s, 32);
        q += __shfl_xor(q, 16); q += __shfl_xor(q, 32);
        if (quad == 0) {
            int ch = wave*32 + g*16 + l16;
            atomicAdd(&stc[ST_M1S + ch], s);
            atomicAdd(&stc[ST_M1Q + ch], q);
        }
    }
}

// ---- GEMM2 (QPB=8, grid 1024): single-stage (all 256 samples staged once, 1 barrier),
// 4 barrier-free MFMA rounds. Reads 8 stats copies for bn1; writes to its split copy.
__global__ void __launch_bounds__(256)
k_gemm2(const unsigned short* __restrict__ y1, const unsigned short* __restrict__ w1p,
        const float* __restrict__ g1m, const float* __restrict__ b1m,
        float* __restrict__ stats, float* __restrict__ mx, float* __restrict__ mn) {
    __shared__ unsigned short ht[256][136];   // 256 samples x 128ch (+pad)
    __shared__ float a1l[128], b1l[128];
    int tid = threadIdx.x;
    float* stc = stats + (size_t)(blockIdx.x & (ST_COPIES-1)) * 1024;
    if (tid < 128) {
        float ssum = 0.f, ssq = 0.f;
        #pragma unroll
        for (int c8 = 0; c8 < ST_COPIES; ++c8) {
            ssum += stats[c8*1024 + ST_M1S + tid];
            ssq  += stats[c8*1024 + ST_M1Q + tid];
        }
        float mean = ssum * (1.f / SAMP);
        float var  = ssq  * (1.f / SAMP) - mean * mean;
        float a = g1m[tid] * rsqrtf(var + EPS_);
        a1l[tid] = a; b1l[tid] = b1m[tid] - mean * a;
    }
    __syncthreads();
    int wave = tid >> 6, lane = tid & 63, quad = lane >> 4, l16 = lane & 15;
    int s = tid >> 3, part = tid & 7;

    float a1r[16], b1r[16];
    {
        const float* ap = &a1l[part * 16];
        const float* bp = &b1l[part * 16];
        #pragma unroll
        for (int i = 0; i < 16; ++i) { a1r[i] = ap[i]; b1r[i] = bp[i]; }
    }
    s8v bfr[4][4];
    #pragma unroll
    for (int g = 0; g < 4; ++g)
        #pragma unroll
        for (int kk = 0; kk < 4; ++kk)
            bfr[g][kk] = *(const s8v*)(w1p + (wave*64 + g*16 + l16)*128 + kk*32 + quad*8);

    // stage ALL 8 queries: issue all loads, then transform+store; one barrier
    size_t base = (size_t)blockIdx.x * 256;
    s8v rv[8][2];
    #pragma unroll
    for (int q = 0; q < 8; ++q) {
        const unsigned short* src = y1 + (base + q*32 + s) * 128 + part * 16;
        rv[q][0] = *(const s8v*)src; rv[q][1] = *(const s8v*)(src + 8);
    }
    #pragma unroll
    for (int q = 0; q < 8; ++q) {
        s8v o0, o1;
        #pragma unroll
        for (int e = 0; e < 8; ++e) {
            float f0 = bf2f((unsigned short)rv[q][0][e]);
            float f1 = bf2f((unsigned short)rv[q][1][e]);
            o0[e] = (short)f2bf(fmaxf(0.f, a1r[e]     * f0 + b1r[e]));
            o1[e] = (short)f2bf(fmaxf(0.f, a1r[8 + e] * f1 + b1r[8 + e]));
        }
        *(s8v*)&ht[q*32 + s][part*16]     = o0;
        *(s8v*)&ht[q*32 + s][part*16 + 8] = o1;
    }
    __syncthreads();   // the only in-loop barrier

    float csum[4] = {}, csq[4] = {};
    for (int r = 0; r < 4; ++r) {
        f32x4 acc[4][4] = {};
        #pragma unroll
        for (int kk = 0; kk < 4; ++kk) {
            s8v at[4];
            #pragma unroll
            for (int t = 0; t < 4; ++t)
                at[t] = *(const s8v*)&ht[r*64 + t*16 + l16][kk*32 + quad*8];
            #pragma unroll
            for (int g = 0; g < 4; ++g)
                #pragma unroll
                for (int t = 0; t < 4; ++t)
                    acc[g][t] = __builtin_amdgcn_mfma_f32_16x16x32_bf16(at[t], bfr[g][kk], acc[g][t], 0, 0, 0);
        }
        #pragma unroll
        for (int g = 0; g < 4; ++g) {
            float sacc = 0.f, qacc = 0.f;
            #pragma unroll
            for (int t = 0; t < 4; ++t)
                #pragma unroll
                for (int e = 0; e < 4; ++e) {
                    float v = acc[g][t][e];
                    sacc += v; qacc = __builtin_fmaf(v, v, qacc);
                }
            csum[g] += sacc; csq[g] += qacc;
            #pragma unroll
            for (int qh = 0; qh < 2; ++qh) {
                int gq = blockIdx.x * 8 + r*2 + qh;
                f32x4 v0 = acc[g][2*qh], v1 = acc[g][2*qh + 1];
                float hi = fmaxf(fmaxf(fmaxf(v0[0], v0[1]), fmaxf(v0[2], v0[3])),
                                 fmaxf(fmaxf(v1[0], v1[1]), fmaxf(v1[2], v1[3])));
                float lo = fminf(fminf(fminf(v0[0], v0[1]), fminf(v0[2], v0[3])),
                                 fminf(fminf(v1[0], v1[1]), fminf(v1[2], v1[3])));
                hi = fmaxf(hi, __shfl_xor(hi, 16)); hi = fmaxf(hi, __shfl_xor(hi, 32));
                lo = fminf(lo, __shfl_xor(lo, 16)); lo = fminf(lo, __shfl_xor(lo, 32));
                if (quad == 0) {
                    int c = wave*64 + g*16 + l16;
                    mx[(size_t)gq * 256 + c] = hi;
                    mn[(size_t)gq * 256 + c] = lo;
                }
            }
        }
    }
    #pragma unroll
    for (int g = 0; g < 4; ++g) {
        float sv = csum[g], q = csq[g];
        sv += __shfl_xor(sv, 16); sv += __shfl_xor(sv, 32);
        q  += __shfl_xor(q, 16);  q  += __shfl_xor(q, 32);
        if (quad == 0) {
            int c = wave*64 + g*16 + l16;
            atomicAdd(&stc[ST_M2S + c], sv);
            atomicAdd(&stc[ST_M2Q + c], q);
        }
    }
}

// ---- bn2 coefficient precompute (1 block): a2/bb2 per channel from the 8 stats copies
__global__ void k_bn2(const float* __restrict__ g2m, const float* __restrict__ b2m,
                      const float* __restrict__ stats, float* __restrict__ ab2) {
    int c = threadIdx.x;   // 256
    float ssum = 0.f, ssq = 0.f;
    #pragma unroll
    for (int c8 = 0; c8 < ST_COPIES; ++c8) {
        ssum += stats[c8*1024 + ST_M2S + c];
        ssq  += stats[c8*1024 + ST_M2Q + c];
    }
    float mean = ssum * (1.f / SAMP);
    float var  = ssq  * (1.f / SAMP) - mean * mean;
    float a = g2m[c] * rsqrtf(var + EPS_);
    ab2[c] = a; ab2[256 + c] = b2m[c] - mean * a;
}

// ---- epilogue: out = relu(a2 * (a2>=0 ? mx : mn) + b2)  (pure elementwise)
__global__ void k_final(const float* __restrict__ mx, const float* __restrict__ mn,
                        const float* __restrict__ ab2, float* __restrict__ out) {
    int i = blockIdx.x * 256 + threadIdx.x;
    int c = i & 255;
    float a = ab2[c], bb = ab2[256 + c];
    float v = (a >= 0.f) ? mx[i] : mn[i];
    out[i] = fmaxf(0.f, a * v + bb);
}

extern "C" void kernel_launch(void* const* d_in, const int* in_sizes, int n_in,
                              void* d_out, int out_size, void* d_ws, size_t ws_size,
                              hipStream_t stream) {
    const float* ffps = (const float*)d_in[0];
    const float* bxyz = (const float*)d_in[1];
    const float* feat = (const float*)d_in[2];
    const float* sw0  = (const float*)d_in[3];
    const float* sg0  = (const float*)d_in[4];
    const float* sb0  = (const float*)d_in[5];
    const float* sw1  = (const float*)d_in[6];
    const float* sg1  = (const float*)d_in[7];
    const float* sb1  = (const float*)d_in[8];
    const float* mw0  = (const float*)d_in[9];
    const float* mg0  = (const float*)d_in[10];
    const float* mb0  = (const float*)d_in[11];
    const float* mw1  = (const float*)d_in[12];
    const float* mg1  = (const float*)d_in[13];
    const float* mb1  = (const float*)d_in[14];
    float* out = (float*)d_out;

    char* ws = (char*)d_ws;
    size_t off = 0;
    auto alloc = [&](size_t bytes) -> void* {
        void* p = ws + off;
        off += (bytes + 255) & ~(size_t)255;
        return p;
    };
    float*          stats = (float*)alloc(ST_COPIES * 1024 * 4);
    float*          t0    = (float*)alloc((size_t)NQ * 64 * 4);
    float*          t1    = (float*)alloc((size_t)NQ * 3 * 4);
    float*          nxyz  = (float*)alloc((size_t)NQ * 3 * 4);
    int*            idxb  = (int*)alloc((size_t)NQ * 32 * 4);
    unsigned short* w0p   = (unsigned short*)alloc(128 * 160 * 2);
    unsigned short* w1p   = (unsigned short*)alloc(256 * 128 * 2);
    unsigned short* featT = (unsigned short*)alloc((size_t)B_ * N_ * 128 * 2);
    unsigned short* y1    = (unsigned short*)alloc((size_t)SAMP * 128 * 2);
    float*          mx    = (float*)alloc((size_t)NQ * 256 * 4);
    float*          mn    = (float*)alloc((size_t)NQ * 256 * 4);
    float*          ab2   = (float*)alloc(512 * 4);
    (void)in_sizes; (void)n_in; (void)out_size; (void)ws_size;

    hipMemsetAsync(stats, 0, ST_COPIES * 1024 * 4, stream);
    k_prep_w   <<<208, 256, 0, stream>>>(mw0, mw1, w0p, w1p);
    k_transpose<<<B_ * 256, 256, 0, stream>>>(feat, featT);
    k_shift0   <<<NQ / 256, 256, 0, stream>>>(ffps, sw0, t0, stats);
    k_shift1   <<<NQ / 256, 256, 0, stream>>>(t0, sw1, sg0, sb0, t1, stats);
    k_shift2   <<<NQ / 256, 256, 0, stream>>>(t1, sg1, sb1, stats, nxyz);
    k_ballq    <<<NQ / 64, 256, 0, stream>>>(bxyz, nxyz, idxb);
    k_gemm1    <<<NQ / 8, 256, 0, stream>>>(featT, bxyz, nxyz, idxb, w0p, y1, stats);
    k_gemm2    <<<NQ / 8, 256, 0, stream>>>(y1, w1p, mg0, mb0, stats, mx, mn);
    k_bn2      <<<1, 256, 0, stream>>>(mg1, mb1, stats, ab2);
    k_final    <<<NQ, 256, 0, stream>>>(mx, mn, ab2, out);
}

// Round 15
// 245.844 us; speedup vs baseline: 1.0192x; 1.0192x over previous
//
#include <hip/hip_runtime.h>
#include <cstddef>
#include <cstdint>

#define B_ 4
#define N_ 16384
#define M_ 2048
#define C_ 128
#define NQ (B_*M_)         // 8192 queries
#define NSAMP 32
#define SAMP (NQ*NSAMP)    // 262144 samples
#define EPS_ 1e-5f
#define R2_ 9.0f

typedef short s8v  __attribute__((ext_vector_type(8)));
typedef short s4v  __attribute__((ext_vector_type(4)));
typedef float f32x4 __attribute__((ext_vector_type(4)));

// stats: 16 contention-split copies of a 1024-float block
#define ST_COPIES 16
#define ST_S0S 0
#define ST_S0Q 64
#define ST_S1S 128
#define ST_S1Q 136
#define ST_M1S 144
#define ST_M1Q 272
#define ST_M2S 400
#define ST_M2Q 656

__device__ __forceinline__ unsigned short f2bf(float f) {
    unsigned int u = __builtin_bit_cast(unsigned int, f);
    u += 0x7fffu + ((u >> 16) & 1u);     // round-to-nearest-even
    return (unsigned short)(u >> 16);
}
__device__ __forceinline__ float bf2f(unsigned short h) {
    unsigned int u = ((unsigned int)h) << 16;
    return __builtin_bit_cast(float, u);
}
__device__ __forceinline__ float fxor(float f, unsigned m) {
    return __builtin_bit_cast(float, __builtin_bit_cast(unsigned, f) ^ m);
}

// ---- prep: reorder+pad mlp_w0 (128x131 -> 128x160 bf16, feat-first), cast mlp_w1 (256x128 bf16)
__global__ void k_prep_w(const float* __restrict__ w0, const float* __restrict__ w1,
                         unsigned short* __restrict__ w0p, unsigned short* __restrict__ w1p) {
    int i = blockIdx.x * 256 + threadIdx.x;
    const int tot0 = 128 * 160;
    if (i < tot0) {
        int o = i / 160, c = i - o * 160;
        float v = 0.f;
        if (c < 128)      v = w0[o * 131 + 3 + c];
        else if (c < 131) v = w0[o * 131 + (c - 128)];
        w0p[i] = f2bf(v);
    }
    int j = i - tot0;
    if (j >= 0 && j < 256 * 128) w1p[j] = f2bf(w1[j]);
}

// ---- transpose backbone_features (B,C,N) f32 -> featT (B,N,C) bf16; vectorized write side
__global__ void k_transpose(const float* __restrict__ feat, unsigned short* __restrict__ featT) {
    __shared__ unsigned short tl[64][130];
    int b  = blockIdx.x >> 8;
    int n0 = (blockIdx.x & 255) * 64;
    const float* src = feat + (size_t)b * C_ * N_;
    int t = threadIdx.x;
    for (int i = 0; i < 32; ++i) {
        int lin = i * 256 + t;
        int c = lin >> 6, n = lin & 63;
        tl[n][c] = f2bf(src[(size_t)c * N_ + n0 + n]);
    }
    __syncthreads();
    unsigned short* dst = featT + ((size_t)b * N_ + n0) * 128;
    #pragma unroll
    for (int i = 0; i < 4; ++i) {
        int lin = i * 256 + t;
        int n = lin >> 4, cg = lin & 15;
        s8v v;
        #pragma unroll
        for (int e = 0; e < 8; ++e) v[e] = (short)tl[n][cg*8 + e];
        *(s8v*)(dst + (size_t)n * 128 + cg * 8) = v;
    }
}

// ---- shift MLP layer 0
__global__ void k_shift0(const float* __restrict__ xyz, const float* __restrict__ w0s,
                         float* __restrict__ t0, float* __restrict__ stats) {
    __shared__ float w[192];
    __shared__ float ps[4][64], pq[4][64];
    int t = threadIdx.x, wave = t >> 6, lane = t & 63;
    if (t < 192) w[t] = w0s[t];
    __syncthreads();
    int p = blockIdx.x * 256 + t;
    float q0 = xyz[p*3], q1 = xyz[p*3+1], q2 = xyz[p*3+2];
    float* orow = t0 + (size_t)p * 64;
    #pragma unroll
    for (int o = 0; o < 64; ++o) {
        float v = w[3*o]*q0 + w[3*o+1]*q1 + w[3*o+2]*q2;
        orow[o] = v;
        float s = v, sq = v * v;
        #pragma unroll
        for (int mk = 32; mk; mk >>= 1) { s += __shfl_xor(s, mk); sq += __shfl_xor(sq, mk); }
        if (lane == 0) { ps[wave][o] = s; pq[wave][o] = sq; }
    }
    __syncthreads();
    if (t < 64) {
        float s = ps[0][t] + ps[1][t] + ps[2][t] + ps[3][t];
        float q = pq[0][t] + pq[1][t] + pq[2][t] + pq[3][t];
        atomicAdd(&stats[ST_S0S + t], s);
        atomicAdd(&stats[ST_S0Q + t], q);
    }
}

// ---- shift layer 1
__global__ void k_shift1(const float* __restrict__ t0, const float* __restrict__ w1s,
                         const float* __restrict__ g0, const float* __restrict__ b0,
                         float* __restrict__ t1, float* __restrict__ stats) {
    __shared__ float aa[64], bb[64], wl[192];
    __shared__ float ps[4][3], pq[4][3];
    int t = threadIdx.x, wave = t >> 6, lane = t & 63;
    if (t < 64) {
        float mean = stats[ST_S0S + t] * (1.f / NQ);
        float var  = stats[ST_S0Q + t] * (1.f / NQ) - mean * mean;
        float a = g0[t] * rsqrtf(var + EPS_);
        aa[t] = a; bb[t] = b0[t] - mean * a;
    }
    if (t < 192) wl[t] = w1s[t];
    __syncthreads();
    int p = blockIdx.x * 256 + t;
    const f32x4* xr = (const f32x4*)(t0 + (size_t)p * 64);
    float v0 = 0.f, v1 = 0.f, v2 = 0.f;
    #pragma unroll
    for (int i = 0; i < 16; ++i) {
        f32x4 x = xr[i];
        #pragma unroll
        for (int j = 0; j < 4; ++j) {
            int c = 4*i + j;
            float h = fmaxf(0.f, aa[c] * x[j] + bb[c]);
            v0 += wl[c] * h; v1 += wl[64 + c] * h; v2 += wl[128 + c] * h;
        }
    }
    t1[p*3] = v0; t1[p*3+1] = v1; t1[p*3+2] = v2;
    float vv[3] = {v0, v1, v2};
    #pragma unroll
    for (int o = 0; o < 3; ++o) {
        float s = vv[o], q = vv[o] * vv[o];
        #pragma unroll
        for (int mk = 32; mk; mk >>= 1) { s += __shfl_xor(s, mk); q += __shfl_xor(q, mk); }
        if (lane == 0) { ps[wave][o] = s; pq[wave][o] = q; }
    }
    __syncthreads();
    if (t < 3) {
        float s = ps[0][t] + ps[1][t] + ps[2][t] + ps[3][t];
        float q = pq[0][t] + pq[1][t] + pq[2][t] + pq[3][t];
        atomicAdd(&stats[ST_S1S + t], s);
        atomicAdd(&stats[ST_S1Q + t], q);
    }
}

// ---- ball query v4 (shift2 folded in): computes new_xyz = relu(bn(t1)) itself,
// writes nxyz for gemm1, then LDS-chunked ordered-first-32 scan.
__global__ void __launch_bounds__(256)
k_ballq(const float* __restrict__ bxyz, const float* __restrict__ t1,
        const float* __restrict__ g1, const float* __restrict__ b1,
        const float* __restrict__ stats, float* __restrict__ nxyz,
        int* __restrict__ idxb) {
    __shared__ float pts[4096 * 3];          // 48 KB
    int tid = threadIdx.x, wave = tid >> 6, lane = tid & 63;
    int b = blockIdx.x >> 5;                 // 32 blocks per batch
    int qbase = blockIdx.x * 64 + wave * 16; // 16 queries per wave
    const float* bp = bxyz + (size_t)b * N_ * 3;
    unsigned long long below = (lane == 63) ? ~0ull >> 1 : ((1ull << lane) - 1ull);

    // bn coefficients (uniform)
    float av[3], bv[3];
    #pragma unroll
    for (int o = 0; o < 3; ++o) {
        float mean = stats[ST_S1S + o] * (1.f / NQ);
        float var  = stats[ST_S1Q + o] * (1.f / NQ) - mean * mean;
        float a = g1[o] * rsqrtf(var + EPS_);
        av[o] = a; bv[o] = b1[o] - mean * a;
    }
    float qx[16], qy[16], qz[16], sq[16];
    int cnt[16], first[16];
    #pragma unroll
    for (int q = 0; q < 16; ++q) {
        qx[q] = fmaxf(0.f, av[0] * t1[(qbase+q)*3]   + bv[0]);
        qy[q] = fmaxf(0.f, av[1] * t1[(qbase+q)*3+1] + bv[1]);
        qz[q] = fmaxf(0.f, av[2] * t1[(qbase+q)*3+2] + bv[2]);
        sq[q] = __fadd_rn(__fadd_rn(__fmul_rn(qx[q],qx[q]), __fmul_rn(qy[q],qy[q])), __fmul_rn(qz[q],qz[q]));
        cnt[q] = 0; first[q] = 0;
    }
    if (lane < 48) {   // write nxyz (identical expression as above)
        int q = lane / 3, o = lane % 3;
        float ao = (o == 0) ? av[0] : ((o == 1) ? av[1] : av[2]);
        float bo = (o == 0) ? bv[0] : ((o == 1) ? bv[1] : bv[2]);
        nxyz[(qbase+q)*3 + o] = fmaxf(0.f, ao * t1[(qbase+q)*3 + o] + bo);
    }

    for (int ch = 0; ch < 4; ++ch) {
        __syncthreads();
        {   // load 4096 points cooperatively, float4-vectorized
            const f32x4* src = (const f32x4*)(bp + ch * 12288);
            f32x4* d4 = (f32x4*)pts;
            #pragma unroll
            for (int i = 0; i < 12; ++i) d4[i*256 + tid] = src[i*256 + tid];
        }
        __syncthreads();
        #pragma unroll
        for (int q = 0; q < 16; ++q) {
            if (cnt[q] >= 32) continue;
            for (int j0 = 0; j0 < 4096 && cnt[q] < 32; j0 += 256) {
                #pragma unroll
                for (int u = 0; u < 4; ++u) {
                    if (cnt[q] < 32) {
                        int jl = j0 + u*64 + lane;
                        float x = pts[jl*3], y = pts[jl*3+1], z = pts[jl*3+2];
                        float sx  = __fadd_rn(__fadd_rn(__fmul_rn(x,x), __fmul_rn(y,y)), __fmul_rn(z,z));
                        float dot = __fadd_rn(__fadd_rn(__fmul_rn(qx[q],x), __fmul_rn(qy[q],y)), __fmul_rn(qz[q],z));
                        float d2  = __fsub_rn(__fadd_rn(sq[q], sx), __fmul_rn(2.0f, dot));
                        unsigned long long m = __ballot(d2 < R2_);
                        if (cnt[q] == 0 && m != 0ull)
                            first[q] = ch*4096 + j0 + u*64 + __ffsll((long long)m) - 1;
                        int pre = cnt[q] + __popcll(m & below);
                        if (((m >> lane) & 1ull) && pre < 32)
                            idxb[(size_t)(qbase+q)*32 + pre] = ch*4096 + jl;
                        cnt[q] += __popcll(m);
                    }
                }
            }
        }
    }
    #pragma unroll
    for (int q = 0; q < 16; ++q) {
        if (cnt[q] < 32) {
            int f = (cnt[q] == 0) ? 0 : first[q];
            for (int k = cnt[q] + lane; k < 32; k += 64) idxb[(size_t)(qbase+q)*32 + k] = f;
        }
    }
}

// ---- GEMM1 (QPB=8, grid 1024): FLIPPED, LDS-staged, 2 queries/round, register prefetch.
__global__ void __launch_bounds__(256)
k_gemm1(const unsigned short* __restrict__ featT, const float* __restrict__ bxyz,
        const float* __restrict__ nxyz, const int* __restrict__ idxb,
        const unsigned short* __restrict__ w0p, unsigned short* __restrict__ y1,
        float* __restrict__ stats) {
    __shared__ unsigned short gt[64][168];
    __shared__ int pidx[256];
    __shared__ float nq[8][3];
    int tid  = threadIdx.x;
    int wave = tid >> 6, lane = tid & 63, quad = lane >> 4, l16 = lane & 15;
    int s2 = tid >> 2, part4 = tid & 3;
    int b = blockIdx.x >> 8;
    float* stc = stats + (size_t)(blockIdx.x & (ST_COPIES-1)) * 1024;

    s8v bfr[2][5];
    #pragma unroll
    for (int g = 0; g < 2; ++g)
        #pragma unroll
        for (int kk = 0; kk < 5; ++kk)
            bfr[g][kk] = *(const s8v*)(w0p + (wave*32 + g*16 + l16)*160 + kk*32 + quad*8);

    pidx[tid] = idxb[blockIdx.x * 256 + tid];
    if (tid < 24) nq[tid / 3][tid % 3] = nxyz[blockIdx.x * 24 + tid];
    if (tid < 64)
        for (int c = 131; c < 160; ++c) gt[tid][c] = 0;
    __syncthreads();

    s8v pv[4]; float prel0 = 0.f, prel1 = 0.f, prel2 = 0.f;
    {
        int pp = pidx[s2];
        const unsigned short* src = featT + ((size_t)(b * N_ + pp)) * 128 + part4 * 32;
        pv[0] = *(const s8v*)src;        pv[1] = *(const s8v*)(src + 8);
        pv[2] = *(const s8v*)(src + 16); pv[3] = *(const s8v*)(src + 24);
        if (tid < 64) {
            int pq_ = pidx[tid];
            const float* bx = bxyz + (size_t)(b * N_ + pq_) * 3;
            int q = tid >> 5;
            prel0 = bx[0] - nq[q][0]; prel1 = bx[1] - nq[q][1]; prel2 = bx[2] - nq[q][2];
        }
    }
    float csum[2] = {}, csq[2] = {};

    for (int r = 0; r < 4; ++r) {
        __syncthreads();
        *(s8v*)&gt[s2][part4*32]      = pv[0];
        *(s8v*)&gt[s2][part4*32 + 8]  = pv[1];
        *(s8v*)&gt[s2][part4*32 + 16] = pv[2];
        *(s8v*)&gt[s2][part4*32 + 24] = pv[3];
        if (tid < 64) {
            gt[tid][128] = f2bf(prel0); gt[tid][129] = f2bf(prel1); gt[tid][130] = f2bf(prel2);
        }
        if (r + 1 < 4) {
            int pp = pidx[(r+1)*64 + s2];
            const unsigned short* src = featT + ((size_t)(b * N_ + pp)) * 128 + part4 * 32;
            pv[0] = *(const s8v*)src;        pv[1] = *(const s8v*)(src + 8);
            pv[2] = *(const s8v*)(src + 16); pv[3] = *(const s8v*)(src + 24);
            if (tid < 64) {
                int pq_ = pidx[(r+1)*64 + tid];
                const float* bx = bxyz + (size_t)(b * N_ + pq_) * 3;
                int q = (r+1)*2 + (tid >> 5);
                prel0 = bx[0] - nq[q][0]; prel1 = bx[1] - nq[q][1]; prel2 = bx[2] - nq[q][2];
            }
        }
        __syncthreads();
        f32x4 acc[2][4] = {};
        #pragma unroll
        for (int kk = 0; kk < 5; ++kk) {
            s8v at[4];
            #pragma unroll
            for (int t = 0; t < 4; ++t)
                at[t] = *(const s8v*)&gt[t*16 + l16][kk*32 + quad*8];
            #pragma unroll
            for (int g = 0; g < 2; ++g)
                #pragma unroll
                for (int t = 0; t < 4; ++t)
                    acc[g][t] = __builtin_amdgcn_mfma_f32_16x16x32_bf16(at[t], bfr[g][kk], acc[g][t], 0, 0, 0);
        }
        size_t sbase = (size_t)blockIdx.x * 256 + r * 64;
        #pragma unroll
        for (int g = 0; g < 2; ++g) {
            int ch = wave*32 + g*16 + l16;
            #pragma unroll
            for (int t = 0; t < 4; ++t)
                #pragma unroll
                for (int rr = 0; rr < 4; ++rr) {
                    float v = acc[g][t][rr];
                    y1[(sbase + t*16 + quad*4 + rr) * 128 + ch] = f2bf(v);
                    csum[g] += v; csq[g] += v * v;
                }
        }
    }
    #pragma unroll
    for (int g = 0; g < 2; ++g) {
        float s = csum[g], q = csq[g];
        s += __shfl_xor(s, 16); s += __shfl_xor(s, 32);
        q += __shfl_xor(q, 16); q += __shfl_xor(q, 32);
        if (quad == 0) {
            int ch = wave*32 + g*16 + l16;
            atomicAdd(&stc[ST_M1S + ch], s);
            atomicAdd(&stc[ST_M1Q + ch], q);
        }
    }
}

// ---- GEMM2 (QPB=8, grid 1024): single-stage, 1 in-loop barrier. Sign-directed
// single reduction per channel (sign(a2)=sign(g2), rsqrt>0): flip-max-flip, exact.
__global__ void __launch_bounds__(256)
k_gemm2(const unsigned short* __restrict__ y1, const unsigned short* __restrict__ w1p,
        const float* __restrict__ g1m, const float* __restrict__ b1m,
        const float* __restrict__ g2m,
        float* __restrict__ stats, float* __restrict__ mv) {
    __shared__ unsigned short ht[256][136];
    __shared__ float a1l[128], b1l[128];
    int tid = threadIdx.x;
    float* stc = stats + (size_t)(blockIdx.x & (ST_COPIES-1)) * 1024;
    if (tid < 128) {
        float ssum = 0.f, ssq = 0.f;
        #pragma unroll
        for (int c8 = 0; c8 < ST_COPIES; ++c8) {
            ssum += stats[c8*1024 + ST_M1S + tid];
            ssq  += stats[c8*1024 + ST_M1Q + tid];
        }
        float mean = ssum * (1.f / SAMP);
        float var  = ssq  * (1.f / SAMP) - mean * mean;
        float a = g1m[tid] * rsqrtf(var + EPS_);
        a1l[tid] = a; b1l[tid] = b1m[tid] - mean * a;
    }
    __syncthreads();
    int wave = tid >> 6, lane = tid & 63, quad = lane >> 4, l16 = lane & 15;
    int s = tid >> 3, part = tid & 7;

    float a1r[16], b1r[16];
    {
        const float* ap = &a1l[part * 16];
        const float* bp = &b1l[part * 16];
        #pragma unroll
        for (int i = 0; i < 16; ++i) { a1r[i] = ap[i]; b1r[i] = bp[i]; }
    }
    s8v bfr[4][4];
    unsigned fmask[4];            // 0 -> keep max; 0x80000000 -> min via sign-flip
    #pragma unroll
    for (int g = 0; g < 4; ++g) {
        int c = wave*64 + g*16 + l16;
        fmask[g] = (g2m[c] >= 0.f) ? 0u : 0x80000000u;
        #pragma unroll
        for (int kk = 0; kk < 4; ++kk)
            bfr[g][kk] = *(const s8v*)(w1p + c*128 + kk*32 + quad*8);
    }

    size_t base = (size_t)blockIdx.x * 256;
    s8v rv[8][2];
    #pragma unroll
    for (int q = 0; q < 8; ++q) {
        const unsigned short* src = y1 + (base + q*32 + s) * 128 + part * 16;
        rv[q][0] = *(const s8v*)src; rv[q][1] = *(const s8v*)(src + 8);
    }
    #pragma unroll
    for (int q = 0; q < 8; ++q) {
        s8v o0, o1;
        #pragma unroll
        for (int e = 0; e < 8; ++e) {
            float f0 = bf2f((unsigned short)rv[q][0][e]);
            float f1 = bf2f((unsigned short)rv[q][1][e]);
            o0[e] = (short)f2bf(fmaxf(0.f, a1r[e]     * f0 + b1r[e]));
            o1[e] = (short)f2bf(fmaxf(0.f, a1r[8 + e] * f1 + b1r[8 + e]));
        }
        *(s8v*)&ht[q*32 + s][part*16]     = o0;
        *(s8v*)&ht[q*32 + s][part*16 + 8] = o1;
    }
    __syncthreads();   // the only in-loop barrier

    float csum[4] = {}, csq[4] = {};
    for (int r = 0; r < 4; ++r) {
        f32x4 acc[4][4] = {};
        #pragma unroll
        for (int kk = 0; kk < 4; ++kk) {
            s8v at[4];
            #pragma unroll
            for (int t = 0; t < 4; ++t)
                at[t] = *(const s8v*)&ht[r*64 + t*16 + l16][kk*32 + quad*8];
            #pragma unroll
            for (int g = 0; g < 4; ++g)
                #pragma unroll
                for (int t = 0; t < 4; ++t)
                    acc[g][t] = __builtin_amdgcn_mfma_f32_16x16x32_bf16(at[t], bfr[g][kk], acc[g][t], 0, 0, 0);
        }
        #pragma unroll
        for (int g = 0; g < 4; ++g) {
            float sacc = 0.f, qacc = 0.f;
            #pragma unroll
            for (int t = 0; t < 4; ++t)
                #pragma unroll
                for (int e = 0; e < 4; ++e) {
                    float v = acc[g][t][e];
                    sacc += v; qacc = __builtin_fmaf(v, v, qacc);
                }
            csum[g] += sacc; csq[g] += qacc;
            #pragma unroll
            for (int qh = 0; qh < 2; ++qh) {
                int gq = blockIdx.x * 8 + r*2 + qh;
                f32x4 v0 = acc[g][2*qh], v1 = acc[g][2*qh + 1];
                float m = fxor(v0[0], fmask[g]);
                #pragma unroll
                for (int e = 1; e < 4; ++e) m = fmaxf(m, fxor(v0[e], fmask[g]));
                #pragma unroll
                for (int e = 0; e < 4; ++e) m = fmaxf(m, fxor(v1[e], fmask[g]));
                m = fmaxf(m, __shfl_xor(m, 16));
                m = fmaxf(m, __shfl_xor(m, 32));
                if (quad == 0) {
                    int c = wave*64 + g*16 + l16;
                    mv[(size_t)gq * 256 + c] = fxor(m, fmask[g]);
                }
            }
        }
    }
    #pragma unroll
    for (int g = 0; g < 4; ++g) {
        float sv = csum[g], q = csq[g];
        sv += __shfl_xor(sv, 16); sv += __shfl_xor(sv, 32);
        q  += __shfl_xor(q, 16);  q  += __shfl_xor(q, 32);
        if (quad == 0) {
            int c = wave*64 + g*16 + l16;
            atomicAdd(&stc[ST_M2S + c], sv);
            atomicAdd(&stc[ST_M2Q + c], q);
        }
    }
}

// ---- bn2 coefficient precompute (1 block)
__global__ void k_bn2(const float* __restrict__ g2m, const float* __restrict__ b2m,
                      const float* __restrict__ stats, float* __restrict__ ab2) {
    int c = threadIdx.x;   // 256
    float ssum = 0.f, ssq = 0.f;
    #pragma unroll
    for (int c8 = 0; c8 < ST_COPIES; ++c8) {
        ssum += stats[c8*1024 + ST_M2S + c];
        ssq  += stats[c8*1024 + ST_M2Q + c];
    }
    float mean = ssum * (1.f / SAMP);
    float var  = ssq  * (1.f / SAMP) - mean * mean;
    float a = g2m[c] * rsqrtf(var + EPS_);
    ab2[c] = a; ab2[256 + c] = b2m[c] - mean * a;
}

// ---- epilogue: out = relu(a2 * mv + b2)  (mv already sign-selected)
__global__ void k_final(const float* __restrict__ mv, const float* __restrict__ ab2,
                        float* __restrict__ out) {
    int i = blockIdx.x * 256 + threadIdx.x;
    int c = i & 255;
    out[i] = fmaxf(0.f, ab2[c] * mv[i] + ab2[256 + c]);
}

extern "C" void kernel_launch(void* const* d_in, const int* in_sizes, int n_in,
                              void* d_out, int out_size, void* d_ws, size_t ws_size,
                              hipStream_t stream) {
    const float* ffps = (const float*)d_in[0];
    const float* bxyz = (const float*)d_in[1];
    const float* feat = (const float*)d_in[2];
    const float* sw0  = (const float*)d_in[3];
    const float* sg0  = (const float*)d_in[4];
    const float* sb0  = (const float*)d_in[5];
    const float* sw1  = (const float*)d_in[6];
    const float* sg1  = (const float*)d_in[7];
    const float* sb1  = (const float*)d_in[8];
    const float* mw0  = (const float*)d_in[9];
    const float* mg0  = (const float*)d_in[10];
    const float* mb0  = (const float*)d_in[11];
    const float* mw1  = (const float*)d_in[12];
    const float* mg1  = (const float*)d_in[13];
    const float* mb1  = (const float*)d_in[14];
    float* out = (float*)d_out;

    char* ws = (char*)d_ws;
    size_t off = 0;
    auto alloc = [&](size_t bytes) -> void* {
        void* p = ws + off;
        off += (bytes + 255) & ~(size_t)255;
        return p;
    };
    float*          stats = (float*)alloc(ST_COPIES * 1024 * 4);
    float*          t0    = (float*)alloc((size_t)NQ * 64 * 4);
    float*          t1    = (float*)alloc((size_t)NQ * 3 * 4);
    float*          nxyz  = (float*)alloc((size_t)NQ * 3 * 4);
    int*            idxb  = (int*)alloc((size_t)NQ * 32 * 4);
    unsigned short* w0p   = (unsigned short*)alloc(128 * 160 * 2);
    unsigned short* w1p   = (unsigned short*)alloc(256 * 128 * 2);
    unsigned short* featT = (unsigned short*)alloc((size_t)B_ * N_ * 128 * 2);
    unsigned short* y1    = (unsigned short*)alloc((size_t)SAMP * 128 * 2);
    float*          mv    = (float*)alloc((size_t)NQ * 256 * 4);
    float*          ab2   = (float*)alloc(512 * 4);
    (void)in_sizes; (void)n_in; (void)out_size; (void)ws_size;

    hipMemsetAsync(stats, 0, ST_COPIES * 1024 * 4, stream);
    k_prep_w   <<<208, 256, 0, stream>>>(mw0, mw1, w0p, w1p);
    k_transpose<<<B_ * 256, 256, 0, stream>>>(feat, featT);
    k_shift0   <<<NQ / 256, 256, 0, stream>>>(ffps, sw0, t0, stats);
    k_shift1   <<<NQ / 256, 256, 0, stream>>>(t0, sw1, sg0, sb0, t1, stats);
    k_ballq    <<<NQ / 64, 256, 0, stream>>>(bxyz, t1, sg1, sb1, stats, nxyz, idxb);
    k_gemm1    <<<NQ / 8, 256, 0, stream>>>(featT, bxyz, nxyz, idxb, w0p, y1, stats);
    k_gemm2    <<<NQ / 8, 256, 0, stream>>>(y1, w1p, mg0, mb0, mg1, stats, mv);
    k_bn2      <<<1, 256, 0, stream>>>(mg1, mb1, stats, ab2);
    k_final    <<<NQ, 256, 0, stream>>>(mv, ab2, out);
}

// Round 17
// 242.953 us; speedup vs baseline: 1.0313x; 1.0119x over previous
//
#include <hip/hip_runtime.h>
#include <cstddef>
#include <cstdint>

#define B_ 4
#define N_ 16384
#define M_ 2048
#define C_ 128
#define NQ (B_*M_)         // 8192 queries
#define NSAMP 32
#define SAMP (NQ*NSAMP)    // 262144 samples
#define EPS_ 1e-5f
#define R2_ 9.0f

typedef short s8v  __attribute__((ext_vector_type(8)));
typedef float f32x4 __attribute__((ext_vector_type(4)));

// stats: 16 contention-split copies of a 1024-float block
#define ST_COPIES 16
#define ST_S0S 0
#define ST_S0Q 64
#define ST_S1S 128
#define ST_S1Q 136
#define ST_M1S 144
#define ST_M1Q 272
#define ST_M2S 400
#define ST_M2Q 656

__device__ __forceinline__ unsigned short f2bf(float f) {
    unsigned int u = __builtin_bit_cast(unsigned int, f);
    u += 0x7fffu + ((u >> 16) & 1u);     // round-to-nearest-even
    return (unsigned short)(u >> 16);
}
__device__ __forceinline__ float bf2f(unsigned short h) {
    unsigned int u = ((unsigned int)h) << 16;
    return __builtin_bit_cast(float, u);
}
__device__ __forceinline__ float fxor(float f, unsigned m) {
    return __builtin_bit_cast(float, __builtin_bit_cast(unsigned, f) ^ m);
}

// ---- prep: reorder+pad mlp_w0 (128x131 -> 128x160 bf16, feat-first), cast mlp_w1 (256x128 bf16)
__global__ void k_prep_w(const float* __restrict__ w0, const float* __restrict__ w1,
                         unsigned short* __restrict__ w0p, unsigned short* __restrict__ w1p) {
    int i = blockIdx.x * 256 + threadIdx.x;
    const int tot0 = 128 * 160;
    if (i < tot0) {
        int o = i / 160, c = i - o * 160;
        float v = 0.f;
        if (c < 128)      v = w0[o * 131 + 3 + c];
        else if (c < 131) v = w0[o * 131 + (c - 128)];
        w0p[i] = f2bf(v);
    }
    int j = i - tot0;
    if (j >= 0 && j < 256 * 128) w1p[j] = f2bf(w1[j]);
}

// ---- transpose backbone_features (B,C,N) f32 -> featT (B,N,C) bf16; vectorized write side
__global__ void k_transpose(const float* __restrict__ feat, unsigned short* __restrict__ featT) {
    __shared__ unsigned short tl[64][130];
    int b  = blockIdx.x >> 8;
    int n0 = (blockIdx.x & 255) * 64;
    const float* src = feat + (size_t)b * C_ * N_;
    int t = threadIdx.x;
    for (int i = 0; i < 32; ++i) {
        int lin = i * 256 + t;
        int c = lin >> 6, n = lin & 63;
        tl[n][c] = f2bf(src[(size_t)c * N_ + n0 + n]);
    }
    __syncthreads();
    unsigned short* dst = featT + ((size_t)b * N_ + n0) * 128;
    #pragma unroll
    for (int i = 0; i < 4; ++i) {
        int lin = i * 256 + t;
        int n = lin >> 4, cg = lin & 15;
        s8v v;
        #pragma unroll
        for (int e = 0; e < 8; ++e) v[e] = (short)tl[n][cg*8 + e];
        *(s8v*)(dst + (size_t)n * 128 + cg * 8) = v;
    }
}

// ---- shift MLP layer 0
__global__ void k_shift0(const float* __restrict__ xyz, const float* __restrict__ w0s,
                         float* __restrict__ t0, float* __restrict__ stats) {
    __shared__ float w[192];
    __shared__ float ps[4][64], pq[4][64];
    int t = threadIdx.x, wave = t >> 6, lane = t & 63;
    if (t < 192) w[t] = w0s[t];
    __syncthreads();
    int p = blockIdx.x * 256 + t;
    float q0 = xyz[p*3], q1 = xyz[p*3+1], q2 = xyz[p*3+2];
    float* orow = t0 + (size_t)p * 64;
    #pragma unroll
    for (int o = 0; o < 64; ++o) {
        float v = w[3*o]*q0 + w[3*o+1]*q1 + w[3*o+2]*q2;
        orow[o] = v;
        float s = v, sq = v * v;
        #pragma unroll
        for (int mk = 32; mk; mk >>= 1) { s += __shfl_xor(s, mk); sq += __shfl_xor(sq, mk); }
        if (lane == 0) { ps[wave][o] = s; pq[wave][o] = sq; }
    }
    __syncthreads();
    if (t < 64) {
        float s = ps[0][t] + ps[1][t] + ps[2][t] + ps[3][t];
        float q = pq[0][t] + pq[1][t] + pq[2][t] + pq[3][t];
        atomicAdd(&stats[ST_S0S + t], s);
        atomicAdd(&stats[ST_S0Q + t], q);
    }
}

// ---- shift layer 1
__global__ void k_shift1(const float* __restrict__ t0, const float* __restrict__ w1s,
                         const float* __restrict__ g0, const float* __restrict__ b0,
                         float* __restrict__ t1, float* __restrict__ stats) {
    __shared__ float aa[64], bb[64], wl[192];
    __shared__ float ps[4][3], pq[4][3];
    int t = threadIdx.x, wave = t >> 6, lane = t & 63;
    if (t < 64) {
        float mean = stats[ST_S0S + t] * (1.f / NQ);
        float var  = stats[ST_S0Q + t] * (1.f / NQ) - mean * mean;
        float a = g0[t] * rsqrtf(var + EPS_);
        aa[t] = a; bb[t] = b0[t] - mean * a;
    }
    if (t < 192) wl[t] = w1s[t];
    __syncthreads();
    int p = blockIdx.x * 256 + t;
    const f32x4* xr = (const f32x4*)(t0 + (size_t)p * 64);
    float v0 = 0.f, v1 = 0.f, v2 = 0.f;
    #pragma unroll
    for (int i = 0; i < 16; ++i) {
        f32x4 x = xr[i];
        #pragma unroll
        for (int j = 0; j < 4; ++j) {
            int c = 4*i + j;
            float h = fmaxf(0.f, aa[c] * x[j] + bb[c]);
            v0 += wl[c] * h; v1 += wl[64 + c] * h; v2 += wl[128 + c] * h;
        }
    }
    t1[p*3] = v0; t1[p*3+1] = v1; t1[p*3+2] = v2;
    float vv[3] = {v0, v1, v2};
    #pragma unroll
    for (int o = 0; o < 3; ++o) {
        float s = vv[o], q = vv[o] * vv[o];
        #pragma unroll
        for (int mk = 32; mk; mk >>= 1) { s += __shfl_xor(s, mk); q += __shfl_xor(q, mk); }
        if (lane == 0) { ps[wave][o] = s; pq[wave][o] = q; }
    }
    __syncthreads();
    if (t < 3) {
        float s = ps[0][t] + ps[1][t] + ps[2][t] + ps[3][t];
        float q = pq[0][t] + pq[1][t] + pq[2][t] + pq[3][t];
        atomicAdd(&stats[ST_S1S + t], s);
        atomicAdd(&stats[ST_S1Q + t], q);
    }
}

// ---- ball query v4 (shift2 folded in): computes new_xyz = relu(bn(t1)) itself,
// writes nxyz for gemm1, then LDS-chunked ordered-first-32 scan.
__global__ void __launch_bounds__(256)
k_ballq(const float* __restrict__ bxyz, const float* __restrict__ t1,
        const float* __restrict__ g1, const float* __restrict__ b1,
        const float* __restrict__ stats, float* __restrict__ nxyz,
        int* __restrict__ idxb) {
    __shared__ float pts[4096 * 3];          // 48 KB
    int tid = threadIdx.x, wave = tid >> 6, lane = tid & 63;
    int b = blockIdx.x >> 5;                 // 32 blocks per batch
    int qbase = blockIdx.x * 64 + wave * 16; // 16 queries per wave
    const float* bp = bxyz + (size_t)b * N_ * 3;
    unsigned long long below = (lane == 63) ? ~0ull >> 1 : ((1ull << lane) - 1ull);

    // bn coefficients (uniform)
    float av[3], bv[3];
    #pragma unroll
    for (int o = 0; o < 3; ++o) {
        float mean = stats[ST_S1S + o] * (1.f / NQ);
        float var  = stats[ST_S1Q + o] * (1.f / NQ) - mean * mean;
        float a = g1[o] * rsqrtf(var + EPS_);
        av[o] = a; bv[o] = b1[o] - mean * a;
    }
    float qx[16], qy[16], qz[16], sq[16];
    int cnt[16], first[16];
    #pragma unroll
    for (int q = 0; q < 16; ++q) {
        qx[q] = fmaxf(0.f, av[0] * t1[(qbase+q)*3]   + bv[0]);
        qy[q] = fmaxf(0.f, av[1] * t1[(qbase+q)*3+1] + bv[1]);
        qz[q] = fmaxf(0.f, av[2] * t1[(qbase+q)*3+2] + bv[2]);
        sq[q] = __fadd_rn(__fadd_rn(__fmul_rn(qx[q],qx[q]), __fmul_rn(qy[q],qy[q])), __fmul_rn(qz[q],qz[q]));
        cnt[q] = 0; first[q] = 0;
    }
    if (lane < 48) {   // write nxyz (identical expression as above)
        int q = lane / 3, o = lane % 3;
        float ao = (o == 0) ? av[0] : ((o == 1) ? av[1] : av[2]);
        float bo = (o == 0) ? bv[0] : ((o == 1) ? bv[1] : bv[2]);
        nxyz[(qbase+q)*3 + o] = fmaxf(0.f, ao * t1[(qbase+q)*3 + o] + bo);
    }

    for (int ch = 0; ch < 4; ++ch) {
        __syncthreads();
        {   // load 4096 points cooperatively, float4-vectorized
            const f32x4* src = (const f32x4*)(bp + ch * 12288);
            f32x4* d4 = (f32x4*)pts;
            #pragma unroll
            for (int i = 0; i < 12; ++i) d4[i*256 + tid] = src[i*256 + tid];
        }
        __syncthreads();
        #pragma unroll
        for (int q = 0; q < 16; ++q) {
            if (cnt[q] >= 32) continue;
            for (int j0 = 0; j0 < 4096 && cnt[q] < 32; j0 += 256) {
                #pragma unroll
                for (int u = 0; u < 4; ++u) {
                    if (cnt[q] < 32) {
                        int jl = j0 + u*64 + lane;
                        float x = pts[jl*3], y = pts[jl*3+1], z = pts[jl*3+2];
                        float sx  = __fadd_rn(__fadd_rn(__fmul_rn(x,x), __fmul_rn(y,y)), __fmul_rn(z,z));
                        float dot = __fadd_rn(__fadd_rn(__fmul_rn(qx[q],x), __fmul_rn(qy[q],y)), __fmul_rn(qz[q],z));
                        float d2  = __fsub_rn(__fadd_rn(sq[q], sx), __fmul_rn(2.0f, dot));
                        unsigned long long m = __ballot(d2 < R2_);
                        if (cnt[q] == 0 && m != 0ull)
                            first[q] = ch*4096 + j0 + u*64 + __ffsll((long long)m) - 1;
                        int pre = cnt[q] + __popcll(m & below);
                        if (((m >> lane) & 1ull) && pre < 32)
                            idxb[(size_t)(qbase+q)*32 + pre] = ch*4096 + jl;
                        cnt[q] += __popcll(m);
                    }
                }
            }
        }
    }
    #pragma unroll
    for (int q = 0; q < 16; ++q) {
        if (cnt[q] < 32) {
            int f = (cnt[q] == 0) ? 0 : first[q];
            for (int k = cnt[q] + lane; k < 32; k += 64) idxb[(size_t)(qbase+q)*32 + k] = f;
        }
    }
}

// ---- GEMM1 (QPB=8, grid 1024): FLIPPED, LDS-staged, 2 queries/round, register prefetch.
__global__ void __launch_bounds__(256)
k_gemm1(const unsigned short* __restrict__ featT, const float* __restrict__ bxyz,
        const float* __restrict__ nxyz, const int* __restrict__ idxb,
        const unsigned short* __restrict__ w0p, unsigned short* __restrict__ y1,
        float* __restrict__ stats) {
    __shared__ unsigned short gt[64][168];
    __shared__ int pidx[256];
    __shared__ float nq[8][3];
    int tid  = threadIdx.x;
    int wave = tid >> 6, lane = tid & 63, quad = lane >> 4, l16 = lane & 15;
    int s2 = tid >> 2, part4 = tid & 3;
    int b = blockIdx.x >> 8;
    float* stc = stats + (size_t)(blockIdx.x & (ST_COPIES-1)) * 1024;

    s8v bfr[2][5];
    #pragma unroll
    for (int g = 0; g < 2; ++g)
        #pragma unroll
        for (int kk = 0; kk < 5; ++kk)
            bfr[g][kk] = *(const s8v*)(w0p + (wave*32 + g*16 + l16)*160 + kk*32 + quad*8);

    pidx[tid] = idxb[blockIdx.x * 256 + tid];
    if (tid < 24) nq[tid / 3][tid % 3] = nxyz[blockIdx.x * 24 + tid];
    if (tid < 64)
        for (int c = 131; c < 160; ++c) gt[tid][c] = 0;
    __syncthreads();

    s8v pv[4]; float prel0 = 0.f, prel1 = 0.f, prel2 = 0.f;
    {
        int pp = pidx[s2];
        const unsigned short* src = featT + ((size_t)(b * N_ + pp)) * 128 + part4 * 32;
        pv[0] = *(const s8v*)src;        pv[1] = *(const s8v*)(src + 8);
        pv[2] = *(const s8v*)(src + 16); pv[3] = *(const s8v*)(src + 24);
        if (tid < 64) {
            int pq_ = pidx[tid];
            const float* bx = bxyz + (size_t)(b * N_ + pq_) * 3;
            int q = tid >> 5;
            prel0 = bx[0] - nq[q][0]; prel1 = bx[1] - nq[q][1]; prel2 = bx[2] - nq[q][2];
        }
    }
    float csum[2] = {}, csq[2] = {};

    for (int r = 0; r < 4; ++r) {
        __syncthreads();
        *(s8v*)&gt[s2][part4*32]      = pv[0];
        *(s8v*)&gt[s2][part4*32 + 8]  = pv[1];
        *(s8v*)&gt[s2][part4*32 + 16] = pv[2];
        *(s8v*)&gt[s2][part4*32 + 24] = pv[3];
        if (tid < 64) {
            gt[tid][128] = f2bf(prel0); gt[tid][129] = f2bf(prel1); gt[tid][130] = f2bf(prel2);
        }
        if (r + 1 < 4) {
            int pp = pidx[(r+1)*64 + s2];
            const unsigned short* src = featT + ((size_t)(b * N_ + pp)) * 128 + part4 * 32;
            pv[0] = *(const s8v*)src;        pv[1] = *(const s8v*)(src + 8);
            pv[2] = *(const s8v*)(src + 16); pv[3] = *(const s8v*)(src + 24);
            if (tid < 64) {
                int pq_ = pidx[(r+1)*64 + tid];
                const float* bx = bxyz + (size_t)(b * N_ + pq_) * 3;
                int q = (r+1)*2 + (tid >> 5);
                prel0 = bx[0] - nq[q][0]; prel1 = bx[1] - nq[q][1]; prel2 = bx[2] - nq[q][2];
            }
        }
        __syncthreads();
        f32x4 acc[2][4] = {};
        #pragma unroll
        for (int kk = 0; kk < 5; ++kk) {
            s8v at[4];
            #pragma unroll
            for (int t = 0; t < 4; ++t)
                at[t] = *(const s8v*)&gt[t*16 + l16][kk*32 + quad*8];
            #pragma unroll
            for (int g = 0; g < 2; ++g)
                #pragma unroll
                for (int t = 0; t < 4; ++t)
                    acc[g][t] = __builtin_amdgcn_mfma_f32_16x16x32_bf16(at[t], bfr[g][kk], acc[g][t], 0, 0, 0);
        }
        size_t sbase = (size_t)blockIdx.x * 256 + r * 64;
        #pragma unroll
        for (int g = 0; g < 2; ++g) {
            int ch = wave*32 + g*16 + l16;
            #pragma unroll
            for (int t = 0; t < 4; ++t)
                #pragma unroll
                for (int rr = 0; rr < 4; ++rr) {
                    float v = acc[g][t][rr];
                    y1[(sbase + t*16 + quad*4 + rr) * 128 + ch] = f2bf(v);
                    csum[g] += v; csq[g] += v * v;
                }
        }
    }
    #pragma unroll
    for (int g = 0; g < 2; ++g) {
        float s = csum[g], q = csq[g];
        s += __shfl_xor(s, 16); s += __shfl_xor(s, 32);
        q += __shfl_xor(q, 16); q += __shfl_xor(q, 32);
        if (quad == 0) {
            int ch = wave*32 + g*16 + l16;
            atomicAdd(&stc[ST_M1S + ch], s);
            atomicAdd(&stc[ST_M1Q + ch], q);
        }
    }
}

// ---- GEMM2 (QPB=8, grid 1024): single-stage, 1 in-loop barrier. Sign-directed
// single reduction per channel (sign(a2)=sign(g2), rsqrt>0): flip-max-flip, exact.
__global__ void __launch_bounds__(256)
k_gemm2(const unsigned short* __restrict__ y1, const unsigned short* __restrict__ w1p,
        const float* __restrict__ g1m, const float* __restrict__ b1m,
        const float* __restrict__ g2m,
        float* __restrict__ stats, float* __restrict__ mv) {
    __shared__ unsigned short ht[256][136];
    __shared__ float a1l[128], b1l[128];
    int tid = threadIdx.x;
    float* stc = stats + (size_t)(blockIdx.x & (ST_COPIES-1)) * 1024;
    if (tid < 128) {
        float ssum = 0.f, ssq = 0.f;
        #pragma unroll
        for (int c8 = 0; c8 < ST_COPIES; ++c8) {
            ssum += stats[c8*1024 + ST_M1S + tid];
            ssq  += stats[c8*1024 + ST_M1Q + tid];
        }
        float mean = ssum * (1.f / SAMP);
        float var  = ssq  * (1.f / SAMP) - mean * mean;
        float a = g1m[tid] * rsqrtf(var + EPS_);
        a1l[tid] = a; b1l[tid] = b1m[tid] - mean * a;
    }
    __syncthreads();
    int wave = tid >> 6, lane = tid & 63, quad = lane >> 4, l16 = lane & 15;
    int s = tid >> 3, part = tid & 7;

    float a1r[16], b1r[16];
    {
        const float* ap = &a1l[part * 16];
        const float* bp = &b1l[part * 16];
        #pragma unroll
        for (int i = 0; i < 16; ++i) { a1r[i] = ap[i]; b1r[i] = bp[i]; }
    }
    s8v bfr[4][4];
    unsigned fmask[4];            // 0 -> keep max; 0x80000000 -> min via sign-flip
    #pragma unroll
    for (int g = 0; g < 4; ++g) {
        int c = wave*64 + g*16 + l16;
        fmask[g] = (g2m[c] >= 0.f) ? 0u : 0x80000000u;
        #pragma unroll
        for (int kk = 0; kk < 4; ++kk)
            bfr[g][kk] = *(const s8v*)(w1p + c*128 + kk*32 + quad*8);
    }

    size_t base = (size_t)blockIdx.x * 256;
    s8v rv[8][2];
    #pragma unroll
    for (int q = 0; q < 8; ++q) {
        const unsigned short* src = y1 + (base + q*32 + s) * 128 + part * 16;
        rv[q][0] = *(const s8v*)src; rv[q][1] = *(const s8v*)(src + 8);
    }
    #pragma unroll
    for (int q = 0; q < 8; ++q) {
        s8v o0, o1;
        #pragma unroll
        for (int e = 0; e < 8; ++e) {
            float f0 = bf2f((unsigned short)rv[q][0][e]);
            float f1 = bf2f((unsigned short)rv[q][1][e]);
            o0[e] = (short)f2bf(fmaxf(0.f, a1r[e]     * f0 + b1r[e]));
            o1[e] = (short)f2bf(fmaxf(0.f, a1r[8 + e] * f1 + b1r[8 + e]));
        }
        *(s8v*)&ht[q*32 + s][part*16]     = o0;
        *(s8v*)&ht[q*32 + s][part*16 + 8] = o1;
    }
    __syncthreads();   // the only in-loop barrier

    float csum[4] = {}, csq[4] = {};
    for (int r = 0; r < 4; ++r) {
        f32x4 acc[4][4] = {};
        #pragma unroll
        for (int kk = 0; kk < 4; ++kk) {
            s8v at[4];
            #pragma unroll
            for (int t = 0; t < 4; ++t)
                at[t] = *(const s8v*)&ht[r*64 + t*16 + l16][kk*32 + quad*8];
            #pragma unroll
            for (int g = 0; g < 4; ++g)
                #pragma unroll
                for (int t = 0; t < 4; ++t)
                    acc[g][t] = __builtin_amdgcn_mfma_f32_16x16x32_bf16(at[t], bfr[g][kk], acc[g][t], 0, 0, 0);
        }
        #pragma unroll
        for (int g = 0; g < 4; ++g) {
            float sacc = 0.f, qacc = 0.f;
            #pragma unroll
            for (int t = 0; t < 4; ++t)
                #pragma unroll
                for (int e = 0; e < 4; ++e) {
                    float v = acc[g][t][e];
                    sacc += v; qacc = __builtin_fmaf(v, v, qacc);
                }
            csum[g] += sacc; csq[g] += qacc;
            #pragma unroll
            for (int qh = 0; qh < 2; ++qh) {
                int gq = blockIdx.x * 8 + r*2 + qh;
                f32x4 v0 = acc[g][2*qh], v1 = acc[g][2*qh + 1];
                float m = fxor(v0[0], fmask[g]);
                #pragma unroll
                for (int e = 1; e < 4; ++e) m = fmaxf(m, fxor(v0[e], fmask[g]));
                #pragma unroll
                for (int e = 0; e < 4; ++e) m = fmaxf(m, fxor(v1[e], fmask[g]));
                m = fmaxf(m, __shfl_xor(m, 16));
                m = fmaxf(m, __shfl_xor(m, 32));
                if (quad == 0) {
                    int c = wave*64 + g*16 + l16;
                    mv[(size_t)gq * 256 + c] = fxor(m, fmask[g]);
                }
            }
        }
    }
    #pragma unroll
    for (int g = 0; g < 4; ++g) {
        float sv = csum[g], q = csq[g];
        sv += __shfl_xor(sv, 16); sv += __shfl_xor(sv, 32);
        q  += __shfl_xor(q, 16);  q  += __shfl_xor(q, 32);
        if (quad == 0) {
            int c = wave*64 + g*16 + l16;
            atomicAdd(&stc[ST_M2S + c], sv);
            atomicAdd(&stc[ST_M2Q + c], q);
        }
    }
}

// ---- epilogue (bn2 folded in): out = relu(a2 * mv + b2); grid 1024 x 8 rows
__global__ void k_final(const float* __restrict__ mv, const float* __restrict__ g2m,
                        const float* __restrict__ b2m, const float* __restrict__ stats,
                        float* __restrict__ out) {
    __shared__ float ab[512];
    int tid = threadIdx.x;
    {
        float ssum = 0.f, ssq = 0.f;
        #pragma unroll
        for (int c8 = 0; c8 < ST_COPIES; ++c8) {
            ssum += stats[c8*1024 + ST_M2S + tid];
            ssq  += stats[c8*1024 + ST_M2Q + tid];
        }
        float mean = ssum * (1.f / SAMP);
        float var  = ssq  * (1.f / SAMP) - mean * mean;
        float a = g2m[tid] * rsqrtf(var + EPS_);
        ab[tid] = a; ab[256 + tid] = b2m[tid] - mean * a;
    }
    __syncthreads();
    size_t base = (size_t)blockIdx.x * 2048;
    float a = ab[tid], bb = ab[256 + tid];
    #pragma unroll
    for (int k = 0; k < 8; ++k) {
        size_t i = base + k*256 + tid;
        out[i] = fmaxf(0.f, a * mv[i] + bb);
    }
}

extern "C" void kernel_launch(void* const* d_in, const int* in_sizes, int n_in,
                              void* d_out, int out_size, void* d_ws, size_t ws_size,
                              hipStream_t stream) {
    const float* ffps = (const float*)d_in[0];
    const float* bxyz = (const float*)d_in[1];
    const float* feat = (const float*)d_in[2];
    const float* sw0  = (const float*)d_in[3];
    const float* sg0  = (const float*)d_in[4];
    const float* sb0  = (const float*)d_in[5];
    const float* sw1  = (const float*)d_in[6];
    const float* sg1  = (const float*)d_in[7];
    const float* sb1  = (const float*)d_in[8];
    const float* mw0  = (const float*)d_in[9];
    const float* mg0  = (const float*)d_in[10];
    const float* mb0  = (const float*)d_in[11];
    const float* mw1  = (const float*)d_in[12];
    const float* mg1  = (const float*)d_in[13];
    const float* mb1  = (const float*)d_in[14];
    float* out = (float*)d_out;

    char* ws = (char*)d_ws;
    size_t off = 0;
    auto alloc = [&](size_t bytes) -> void* {
        void* p = ws + off;
        off += (bytes + 255) & ~(size_t)255;
        return p;
    };
    float*          stats = (float*)alloc(ST_COPIES * 1024 * 4);
    float*          t0    = (float*)alloc((size_t)NQ * 64 * 4);
    float*          t1    = (float*)alloc((size_t)NQ * 3 * 4);
    float*          nxyz  = (float*)alloc((size_t)NQ * 3 * 4);
    int*            idxb  = (int*)alloc((size_t)NQ * 32 * 4);
    unsigned short* w0p   = (unsigned short*)alloc(128 * 160 * 2);
    unsigned short* w1p   = (unsigned short*)alloc(256 * 128 * 2);
    unsigned short* featT = (unsigned short*)alloc((size_t)B_ * N_ * 128 * 2);
    unsigned short* y1    = (unsigned short*)alloc((size_t)SAMP * 128 * 2);
    float*          mv    = (float*)alloc((size_t)NQ * 256 * 4);
    (void)in_sizes; (void)n_in; (void)out_size; (void)ws_size;

    hipMemsetAsync(stats, 0, ST_COPIES * 1024 * 4, stream);
    k_prep_w   <<<208, 256, 0, stream>>>(mw0, mw1, w0p, w1p);
    k_transpose<<<B_ * 256, 256, 0, stream>>>(feat, featT);
    k_shift0   <<<NQ / 256, 256, 0, stream>>>(ffps, sw0, t0, stats);
    k_shift1   <<<NQ / 256, 256, 0, stream>>>(t0, sw1, sg0, sb0, t1, stats);
    k_ballq    <<<NQ / 64, 256, 0, stream>>>(bxyz, t1, sg1, sb1, stats, nxyz, idxb);
    k_gemm1    <<<NQ / 8, 256, 0, stream>>>(featT, bxyz, nxyz, idxb, w0p, y1, stats);
    k_gemm2    <<<NQ / 8, 256, 0, stream>>>(y1, w1p, mg0, mb0, mg1, stats, mv);
    k_final    <<<NQ / 8, 256, 0, stream>>>(mv, mg1, mb1, stats, out);
}

// Round 18
// 235.765 us; speedup vs baseline: 1.0628x; 1.0305x over previous
//
#include <hip/hip_runtime.h>
#include <cstddef>
#include <cstdint>

#define B_ 4
#define N_ 16384
#define M_ 2048
#define C_ 128
#define NQ (B_*M_)         // 8192 queries
#define NSAMP 32
#define SAMP (NQ*NSAMP)    // 262144 samples
#define EPS_ 1e-5f
#define R2_ 9.0f

typedef short s8v  __attribute__((ext_vector_type(8)));
typedef float f32x4 __attribute__((ext_vector_type(4)));

// stats: 16 contention-split copies of a 1024-float block
#define ST_COPIES 16
#define ST_S0S 0
#define ST_S0Q 64
#define ST_S1S 128
#define ST_S1Q 136
#define ST_M1S 144
#define ST_M1Q 272
#define ST_M2S 400
#define ST_M2Q 656

__device__ __forceinline__ unsigned short f2bf(float f) {
    unsigned int u = __builtin_bit_cast(unsigned int, f);
    u += 0x7fffu + ((u >> 16) & 1u);     // round-to-nearest-even
    return (unsigned short)(u >> 16);
}
__device__ __forceinline__ float bf2f(unsigned short h) {
    unsigned int u = ((unsigned int)h) << 16;
    return __builtin_bit_cast(float, u);
}
__device__ __forceinline__ float fxor(float f, unsigned m) {
    return __builtin_bit_cast(float, __builtin_bit_cast(unsigned, f) ^ m);
}

// ---- merged head kernel: blocks [0,208) prep_w | [208,1232) transpose | [1232,1264) shift0
__global__ void __launch_bounds__(256)
k_head(const float* __restrict__ w0, const float* __restrict__ w1,
       unsigned short* __restrict__ w0p, unsigned short* __restrict__ w1p,
       const float* __restrict__ feat, unsigned short* __restrict__ featT,
       const float* __restrict__ xyz, const float* __restrict__ w0s,
       float* __restrict__ t0, float* __restrict__ stats) {
    __shared__ unsigned short tl[64][130];   // used by transpose branch (16.6 KB); also aliased below
    int bid = blockIdx.x, t = threadIdx.x;
    if (bid < 208) {
        // ---- prep_w
        int i = bid * 256 + t;
        const int tot0 = 128 * 160;
        if (i < tot0) {
            int o = i / 160, c = i - o * 160;
            float v = 0.f;
            if (c < 128)      v = w0[o * 131 + 3 + c];
            else if (c < 131) v = w0[o * 131 + (c - 128)];
            w0p[i] = f2bf(v);
        }
        int j = i - tot0;
        if (j >= 0 && j < 256 * 128) w1p[j] = f2bf(w1[j]);
    } else if (bid < 1232) {
        // ---- transpose
        int tb = bid - 208;
        int b  = tb >> 8;
        int n0 = (tb & 255) * 64;
        const float* src = feat + (size_t)b * C_ * N_;
        for (int i = 0; i < 32; ++i) {
            int lin = i * 256 + t;
            int c = lin >> 6, n = lin & 63;
            tl[n][c] = f2bf(src[(size_t)c * N_ + n0 + n]);
        }
        __syncthreads();
        unsigned short* dst = featT + ((size_t)b * N_ + n0) * 128;
        #pragma unroll
        for (int i = 0; i < 4; ++i) {
            int lin = i * 256 + t;
            int n = lin >> 4, cg = lin & 15;
            s8v v;
            #pragma unroll
            for (int e = 0; e < 8; ++e) v[e] = (short)tl[n][cg*8 + e];
            *(s8v*)(dst + (size_t)n * 128 + cg * 8) = v;
        }
    } else {
        // ---- shift0 (32 blocks)
        float* w  = (float*)&tl[0][0];           // 192 floats
        float* ps = w + 192;                      // 4*64
        float* pq = ps + 256;                     // 4*64
        int wave = t >> 6, lane = t & 63;
        if (t < 192) w[t] = w0s[t];
        __syncthreads();
        int p = (bid - 1232) * 256 + t;
        float q0 = xyz[p*3], q1 = xyz[p*3+1], q2 = xyz[p*3+2];
        float* orow = t0 + (size_t)p * 64;
        #pragma unroll
        for (int o = 0; o < 64; ++o) {
            float v = w[3*o]*q0 + w[3*o+1]*q1 + w[3*o+2]*q2;
            orow[o] = v;
            float s = v, sq = v * v;
            #pragma unroll
            for (int mk = 32; mk; mk >>= 1) { s += __shfl_xor(s, mk); sq += __shfl_xor(sq, mk); }
            if (lane == 0) { ps[wave*64 + o] = s; pq[wave*64 + o] = sq; }
        }
        __syncthreads();
        if (t < 64) {
            float s = ps[t] + ps[64+t] + ps[128+t] + ps[192+t];
            float q = pq[t] + pq[64+t] + pq[128+t] + pq[192+t];
            atomicAdd(&stats[ST_S0S + t], s);
            atomicAdd(&stats[ST_S0Q + t], q);
        }
    }
}

// ---- shift layer 1
__global__ void k_shift1(const float* __restrict__ t0, const float* __restrict__ w1s,
                         const float* __restrict__ g0, const float* __restrict__ b0,
                         float* __restrict__ t1, float* __restrict__ stats) {
    __shared__ float aa[64], bb[64], wl[192];
    __shared__ float ps[4][3], pq[4][3];
    int t = threadIdx.x, wave = t >> 6, lane = t & 63;
    if (t < 64) {
        float mean = stats[ST_S0S + t] * (1.f / NQ);
        float var  = stats[ST_S0Q + t] * (1.f / NQ) - mean * mean;
        float a = g0[t] * rsqrtf(var + EPS_);
        aa[t] = a; bb[t] = b0[t] - mean * a;
    }
    if (t < 192) wl[t] = w1s[t];
    __syncthreads();
    int p = blockIdx.x * 256 + t;
    const f32x4* xr = (const f32x4*)(t0 + (size_t)p * 64);
    float v0 = 0.f, v1 = 0.f, v2 = 0.f;
    #pragma unroll
    for (int i = 0; i < 16; ++i) {
        f32x4 x = xr[i];
        #pragma unroll
        for (int j = 0; j < 4; ++j) {
            int c = 4*i + j;
            float h = fmaxf(0.f, aa[c] * x[j] + bb[c]);
            v0 += wl[c] * h; v1 += wl[64 + c] * h; v2 += wl[128 + c] * h;
        }
    }
    t1[p*3] = v0; t1[p*3+1] = v1; t1[p*3+2] = v2;
    float vv[3] = {v0, v1, v2};
    #pragma unroll
    for (int o = 0; o < 3; ++o) {
        float s = vv[o], q = vv[o] * vv[o];
        #pragma unroll
        for (int mk = 32; mk; mk >>= 1) { s += __shfl_xor(s, mk); q += __shfl_xor(q, mk); }
        if (lane == 0) { ps[wave][o] = s; pq[wave][o] = q; }
    }
    __syncthreads();
    if (t < 3) {
        float s = ps[0][t] + ps[1][t] + ps[2][t] + ps[3][t];
        float q = pq[0][t] + pq[1][t] + pq[2][t] + pq[3][t];
        atomicAdd(&stats[ST_S1S + t], s);
        atomicAdd(&stats[ST_S1Q + t], q);
    }
}

// ---- ball query v5: 256 blocks x 32 queries (8 per wave), LDS-chunked scan
__global__ void __launch_bounds__(256)
k_ballq(const float* __restrict__ bxyz, const float* __restrict__ t1,
        const float* __restrict__ g1, const float* __restrict__ b1,
        const float* __restrict__ stats, float* __restrict__ nxyz,
        int* __restrict__ idxb) {
    __shared__ float pts[4096 * 3];          // 48 KB
    int tid = threadIdx.x, wave = tid >> 6, lane = tid & 63;
    int b = blockIdx.x >> 6;                 // 64 blocks per batch
    int qbase = blockIdx.x * 32 + wave * 8;  // 8 queries per wave
    const float* bp = bxyz + (size_t)b * N_ * 3;
    unsigned long long below = (lane == 63) ? ~0ull >> 1 : ((1ull << lane) - 1ull);

    float av[3], bv[3];
    #pragma unroll
    for (int o = 0; o < 3; ++o) {
        float mean = stats[ST_S1S + o] * (1.f / NQ);
        float var  = stats[ST_S1Q + o] * (1.f / NQ) - mean * mean;
        float a = g1[o] * rsqrtf(var + EPS_);
        av[o] = a; bv[o] = b1[o] - mean * a;
    }
    float qx[8], qy[8], qz[8], sq[8];
    int cnt[8], first[8];
    #pragma unroll
    for (int q = 0; q < 8; ++q) {
        qx[q] = fmaxf(0.f, av[0] * t1[(qbase+q)*3]   + bv[0]);
        qy[q] = fmaxf(0.f, av[1] * t1[(qbase+q)*3+1] + bv[1]);
        qz[q] = fmaxf(0.f, av[2] * t1[(qbase+q)*3+2] + bv[2]);
        sq[q] = __fadd_rn(__fadd_rn(__fmul_rn(qx[q],qx[q]), __fmul_rn(qy[q],qy[q])), __fmul_rn(qz[q],qz[q]));
        cnt[q] = 0; first[q] = 0;
    }
    if (lane < 24) {   // write nxyz (identical expression)
        int q = lane / 3, o = lane % 3;
        float ao = (o == 0) ? av[0] : ((o == 1) ? av[1] : av[2]);
        float bo = (o == 0) ? bv[0] : ((o == 1) ? bv[1] : bv[2]);
        nxyz[(qbase+q)*3 + o] = fmaxf(0.f, ao * t1[(qbase+q)*3 + o] + bo);
    }

    for (int ch = 0; ch < 4; ++ch) {
        __syncthreads();
        {
            const f32x4* src = (const f32x4*)(bp + ch * 12288);
            f32x4* d4 = (f32x4*)pts;
            #pragma unroll
            for (int i = 0; i < 12; ++i) d4[i*256 + tid] = src[i*256 + tid];
        }
        __syncthreads();
        #pragma unroll
        for (int q = 0; q < 8; ++q) {
            if (cnt[q] >= 32) continue;
            for (int j0 = 0; j0 < 4096 && cnt[q] < 32; j0 += 256) {
                #pragma unroll
                for (int u = 0; u < 4; ++u) {
                    if (cnt[q] < 32) {
                        int jl = j0 + u*64 + lane;
                        float x = pts[jl*3], y = pts[jl*3+1], z = pts[jl*3+2];
                        float sx  = __fadd_rn(__fadd_rn(__fmul_rn(x,x), __fmul_rn(y,y)), __fmul_rn(z,z));
                        float dot = __fadd_rn(__fadd_rn(__fmul_rn(qx[q],x), __fmul_rn(qy[q],y)), __fmul_rn(qz[q],z));
                        float d2  = __fsub_rn(__fadd_rn(sq[q], sx), __fmul_rn(2.0f, dot));
                        unsigned long long m = __ballot(d2 < R2_);
                        if (cnt[q] == 0 && m != 0ull)
                            first[q] = ch*4096 + j0 + u*64 + __ffsll((long long)m) - 1;
                        int pre = cnt[q] + __popcll(m & below);
                        if (((m >> lane) & 1ull) && pre < 32)
                            idxb[(size_t)(qbase+q)*32 + pre] = ch*4096 + jl;
                        cnt[q] += __popcll(m);
                    }
                }
            }
        }
    }
    #pragma unroll
    for (int q = 0; q < 8; ++q) {
        if (cnt[q] < 32) {
            int f = (cnt[q] == 0) ? 0 : first[q];
            for (int k = cnt[q] + lane; k < 32; k += 64) idxb[(size_t)(qbase+q)*32 + k] = f;
        }
    }
}

// ---- GEMM1 (QPB=8, grid 1024): FLIPPED, LDS-staged, 2 queries/round, register prefetch.
__global__ void __launch_bounds__(256)
k_gemm1(const unsigned short* __restrict__ featT, const float* __restrict__ bxyz,
        const float* __restrict__ nxyz, const int* __restrict__ idxb,
        const unsigned short* __restrict__ w0p, unsigned short* __restrict__ y1,
        float* __restrict__ stats) {
    __shared__ unsigned short gt[64][168];
    __shared__ int pidx[256];
    __shared__ float nq[8][3];
    int tid  = threadIdx.x;
    int wave = tid >> 6, lane = tid & 63, quad = lane >> 4, l16 = lane & 15;
    int s2 = tid >> 2, part4 = tid & 3;
    int b = blockIdx.x >> 8;
    float* stc = stats + (size_t)(blockIdx.x & (ST_COPIES-1)) * 1024;

    s8v bfr[2][5];
    #pragma unroll
    for (int g = 0; g < 2; ++g)
        #pragma unroll
        for (int kk = 0; kk < 5; ++kk)
            bfr[g][kk] = *(const s8v*)(w0p + (wave*32 + g*16 + l16)*160 + kk*32 + quad*8);

    pidx[tid] = idxb[blockIdx.x * 256 + tid];
    if (tid < 24) nq[tid / 3][tid % 3] = nxyz[blockIdx.x * 24 + tid];
    if (tid < 64)
        for (int c = 131; c < 160; ++c) gt[tid][c] = 0;
    __syncthreads();

    s8v pv[4]; float prel0 = 0.f, prel1 = 0.f, prel2 = 0.f;
    {
        int pp = pidx[s2];
        const unsigned short* src = featT + ((size_t)(b * N_ + pp)) * 128 + part4 * 32;
        pv[0] = *(const s8v*)src;        pv[1] = *(const s8v*)(src + 8);
        pv[2] = *(const s8v*)(src + 16); pv[3] = *(const s8v*)(src + 24);
        if (tid < 64) {
            int pq_ = pidx[tid];
            const float* bx = bxyz + (size_t)(b * N_ + pq_) * 3;
            int q = tid >> 5;
            prel0 = bx[0] - nq[q][0]; prel1 = bx[1] - nq[q][1]; prel2 = bx[2] - nq[q][2];
        }
    }
    float csum[2] = {}, csq[2] = {};

    for (int r = 0; r < 4; ++r) {
        __syncthreads();
        *(s8v*)&gt[s2][part4*32]      = pv[0];
        *(s8v*)&gt[s2][part4*32 + 8]  = pv[1];
        *(s8v*)&gt[s2][part4*32 + 16] = pv[2];
        *(s8v*)&gt[s2][part4*32 + 24] = pv[3];
        if (tid < 64) {
            gt[tid][128] = f2bf(prel0); gt[tid][129] = f2bf(prel1); gt[tid][130] = f2bf(prel2);
        }
        if (r + 1 < 4) {
            int pp = pidx[(r+1)*64 + s2];
            const unsigned short* src = featT + ((size_t)(b * N_ + pp)) * 128 + part4 * 32;
            pv[0] = *(const s8v*)src;        pv[1] = *(const s8v*)(src + 8);
            pv[2] = *(const s8v*)(src + 16); pv[3] = *(const s8v*)(src + 24);
            if (tid < 64) {
                int pq_ = pidx[(r+1)*64 + tid];
                const float* bx = bxyz + (size_t)(b * N_ + pq_) * 3;
                int q = (r+1)*2 + (tid >> 5);
                prel0 = bx[0] - nq[q][0]; prel1 = bx[1] - nq[q][1]; prel2 = bx[2] - nq[q][2];
            }
        }
        __syncthreads();
        f32x4 acc[2][4] = {};
        #pragma unroll
        for (int kk = 0; kk < 5; ++kk) {
            s8v at[4];
            #pragma unroll
            for (int t = 0; t < 4; ++t)
                at[t] = *(const s8v*)&gt[t*16 + l16][kk*32 + quad*8];
            #pragma unroll
            for (int g = 0; g < 2; ++g)
                #pragma unroll
                for (int t = 0; t < 4; ++t)
                    acc[g][t] = __builtin_amdgcn_mfma_f32_16x16x32_bf16(at[t], bfr[g][kk], acc[g][t], 0, 0, 0);
        }
        size_t sbase = (size_t)blockIdx.x * 256 + r * 64;
        #pragma unroll
        for (int g = 0; g < 2; ++g) {
            int ch = wave*32 + g*16 + l16;
            #pragma unroll
            for (int t = 0; t < 4; ++t)
                #pragma unroll
                for (int rr = 0; rr < 4; ++rr) {
                    float v = acc[g][t][rr];
                    y1[(sbase + t*16 + quad*4 + rr) * 128 + ch] = f2bf(v);
                    csum[g] += v; csq[g] += v * v;
                }
        }
    }
    #pragma unroll
    for (int g = 0; g < 2; ++g) {
        float s = csum[g], q = csq[g];
        s += __shfl_xor(s, 16); s += __shfl_xor(s, 32);
        q += __shfl_xor(q, 16); q += __shfl_xor(q, 32);
        if (quad == 0) {
            int ch = wave*32 + g*16 + l16;
            atomicAdd(&stc[ST_M1S + ch], s);
            atomicAdd(&stc[ST_M1Q + ch], q);
        }
    }
}

// ---- GEMM2 (QPB=8, grid 1024): single-stage, 1 in-loop barrier. Sign-directed
// single reduction per channel (sign(a2)=sign(g2), rsqrt>0): flip-max-flip, exact.
__global__ void __launch_bounds__(256)
k_gemm2(const unsigned short* __restrict__ y1, const unsigned short* __restrict__ w1p,
        const float* __restrict__ g1m, const float* __restrict__ b1m,
        const float* __restrict__ g2m,
        float* __restrict__ stats, float* __restrict__ mv) {
    __shared__ unsigned short ht[256][136];
    __shared__ float a1l[128], b1l[128];
    int tid = threadIdx.x;
    float* stc = stats + (size_t)(blockIdx.x & (ST_COPIES-1)) * 1024;
    if (tid < 128) {
        float ssum = 0.f, ssq = 0.f;
        #pragma unroll
        for (int c8 = 0; c8 < ST_COPIES; ++c8) {
            ssum += stats[c8*1024 + ST_M1S + tid];
            ssq  += stats[c8*1024 + ST_M1Q + tid];
        }
        float mean = ssum * (1.f / SAMP);
        float var  = ssq  * (1.f / SAMP) - mean * mean;
        float a = g1m[tid] * rsqrtf(var + EPS_);
        a1l[tid] = a; b1l[tid] = b1m[tid] - mean * a;
    }
    __syncthreads();
    int wave = tid >> 6, lane = tid & 63, quad = lane >> 4, l16 = lane & 15;
    int s = tid >> 3, part = tid & 7;

    float a1r[16], b1r[16];
    {
        const float* ap = &a1l[part * 16];
        const float* bp = &b1l[part * 16];
        #pragma unroll
        for (int i = 0; i < 16; ++i) { a1r[i] = ap[i]; b1r[i] = bp[i]; }
    }
    s8v bfr[4][4];
    unsigned fmask[4];            // 0 -> keep max; 0x80000000 -> min via sign-flip
    #pragma unroll
    for (int g = 0; g < 4; ++g) {
        int c = wave*64 + g*16 + l16;
        fmask[g] = (g2m[c] >= 0.f) ? 0u : 0x80000000u;
        #pragma unroll
        for (int kk = 0; kk < 4; ++kk)
            bfr[g][kk] = *(const s8v*)(w1p + c*128 + kk*32 + quad*8);
    }

    size_t base = (size_t)blockIdx.x * 256;
    s8v rv[8][2];
    #pragma unroll
    for (int q = 0; q < 8; ++q) {
        const unsigned short* src = y1 + (base + q*32 + s) * 128 + part * 16;
        rv[q][0] = *(const s8v*)src; rv[q][1] = *(const s8v*)(src + 8);
    }
    #pragma unroll
    for (int q = 0; q < 8; ++q) {
        s8v o0, o1;
        #pragma unroll
        for (int e = 0; e < 8; ++e) {
            float f0 = bf2f((unsigned short)rv[q][0][e]);
            float f1 = bf2f((unsigned short)rv[q][1][e]);
            o0[e] = (short)f2bf(fmaxf(0.f, a1r[e]     * f0 + b1r[e]));
            o1[e] = (short)f2bf(fmaxf(0.f, a1r[8 + e] * f1 + b1r[8 + e]));
        }
        *(s8v*)&ht[q*32 + s][part*16]     = o0;
        *(s8v*)&ht[q*32 + s][part*16 + 8] = o1;
    }
    __syncthreads();   // the only in-loop barrier

    float csum[4] = {}, csq[4] = {};
    for (int r = 0; r < 4; ++r) {
        f32x4 acc[4][4] = {};
        #pragma unroll
        for (int kk = 0; kk < 4; ++kk) {
            s8v at[4];
            #pragma unroll
            for (int t = 0; t < 4; ++t)
                at[t] = *(const s8v*)&ht[r*64 + t*16 + l16][kk*32 + quad*8];
            #pragma unroll
            for (int g = 0; g < 4; ++g)
                #pragma unroll
                for (int t = 0; t < 4; ++t)
                    acc[g][t] = __builtin_amdgcn_mfma_f32_16x16x32_bf16(at[t], bfr[g][kk], acc[g][t], 0, 0, 0);
        }
        #pragma unroll
        for (int g = 0; g < 4; ++g) {
            float sacc = 0.f, qacc = 0.f;
            #pragma unroll
            for (int t = 0; t < 4; ++t)
                #pragma unroll
                for (int e = 0; e < 4; ++e) {
                    float v = acc[g][t][e];
                    sacc += v; qacc = __builtin_fmaf(v, v, qacc);
                }
            csum[g] += sacc; csq[g] += qacc;
            #pragma unroll
            for (int qh = 0; qh < 2; ++qh) {
                int gq = blockIdx.x * 8 + r*2 + qh;
                f32x4 v0 = acc[g][2*qh], v1 = acc[g][2*qh + 1];
                float m = fxor(v0[0], fmask[g]);
                #pragma unroll
                for (int e = 1; e < 4; ++e) m = fmaxf(m, fxor(v0[e], fmask[g]));
                #pragma unroll
                for (int e = 0; e < 4; ++e) m = fmaxf(m, fxor(v1[e], fmask[g]));
                m = fmaxf(m, __shfl_xor(m, 16));
                m = fmaxf(m, __shfl_xor(m, 32));
                if (quad == 0) {
                    int c = wave*64 + g*16 + l16;
                    mv[(size_t)gq * 256 + c] = fxor(m, fmask[g]);
                }
            }
        }
    }
    #pragma unroll
    for (int g = 0; g < 4; ++g) {
        float sv = csum[g], q = csq[g];
        sv += __shfl_xor(sv, 16); sv += __shfl_xor(sv, 32);
        q  += __shfl_xor(q, 16);  q  += __shfl_xor(q, 32);
        if (quad == 0) {
            int c = wave*64 + g*16 + l16;
            atomicAdd(&stc[ST_M2S + c], sv);
            atomicAdd(&stc[ST_M2Q + c], q);
        }
    }
}

// ---- epilogue (bn2 folded in): out = relu(a2 * mv + b2); grid 1024 x 8 rows
__global__ void k_final(const float* __restrict__ mv, const float* __restrict__ g2m,
                        const float* __restrict__ b2m, const float* __restrict__ stats,
                        float* __restrict__ out) {
    __shared__ float ab[512];
    int tid = threadIdx.x;
    {
        float ssum = 0.f, ssq = 0.f;
        #pragma unroll
        for (int c8 = 0; c8 < ST_COPIES; ++c8) {
            ssum += stats[c8*1024 + ST_M2S + tid];
            ssq  += stats[c8*1024 + ST_M2Q + tid];
        }
        float mean = ssum * (1.f / SAMP);
        float var  = ssq  * (1.f / SAMP) - mean * mean;
        float a = g2m[tid] * rsqrtf(var + EPS_);
        ab[tid] = a; ab[256 + tid] = b2m[tid] - mean * a;
    }
    __syncthreads();
    size_t base = (size_t)blockIdx.x * 2048;
    float a = ab[tid], bb = ab[256 + tid];
    #pragma unroll
    for (int k = 0; k < 8; ++k) {
        size_t i = base + k*256 + tid;
        out[i] = fmaxf(0.f, a * mv[i] + bb);
    }
}

extern "C" void kernel_launch(void* const* d_in, const int* in_sizes, int n_in,
                              void* d_out, int out_size, void* d_ws, size_t ws_size,
                              hipStream_t stream) {
    const float* ffps = (const float*)d_in[0];
    const float* bxyz = (const float*)d_in[1];
    const float* feat = (const float*)d_in[2];
    const float* sw0  = (const float*)d_in[3];
    const float* sg0  = (const float*)d_in[4];
    const float* sb0  = (const float*)d_in[5];
    const float* sw1  = (const float*)d_in[6];
    const float* sg1  = (const float*)d_in[7];
    const float* sb1  = (const float*)d_in[8];
    const float* mw0  = (const float*)d_in[9];
    const float* mg0  = (const float*)d_in[10];
    const float* mb0  = (const float*)d_in[11];
    const float* mw1  = (const float*)d_in[12];
    const float* mg1  = (const float*)d_in[13];
    const float* mb1  = (const float*)d_in[14];
    float* out = (float*)d_out;

    char* ws = (char*)d_ws;
    size_t off = 0;
    auto alloc = [&](size_t bytes) -> void* {
        void* p = ws + off;
        off += (bytes + 255) & ~(size_t)255;
        return p;
    };
    float*          stats = (float*)alloc(ST_COPIES * 1024 * 4);
    float*          t0    = (float*)alloc((size_t)NQ * 64 * 4);
    float*          t1    = (float*)alloc((size_t)NQ * 3 * 4);
    float*          nxyz  = (float*)alloc((size_t)NQ * 3 * 4);
    int*            idxb  = (int*)alloc((size_t)NQ * 32 * 4);
    unsigned short* w0p   = (unsigned short*)alloc(128 * 160 * 2);
    unsigned short* w1p   = (unsigned short*)alloc(256 * 128 * 2);
    unsigned short* featT = (unsigned short*)alloc((size_t)B_ * N_ * 128 * 2);
    unsigned short* y1    = (unsigned short*)alloc((size_t)SAMP * 128 * 2);
    float*          mv    = (float*)alloc((size_t)NQ * 256 * 4);
    (void)in_sizes; (void)n_in; (void)out_size; (void)ws_size;

    hipMemsetAsync(stats, 0, ST_COPIES * 1024 * 4, stream);
    k_head   <<<1264, 256, 0, stream>>>(mw0, mw1, w0p, w1p, feat, featT, ffps, sw0, t0, stats);
    k_shift1 <<<NQ / 256, 256, 0, stream>>>(t0, sw1, sg0, sb0, t1, stats);
    k_ballq  <<<NQ / 32, 256, 0, stream>>>(bxyz, t1, sg1, sb1, stats, nxyz, idxb);
    k_gemm1  <<<NQ / 8, 256, 0, stream>>>(featT, bxyz, nxyz, idxb, w0p, y1, stats);
    k_gemm2  <<<NQ / 8, 256, 0, stream>>>(y1, w1p, mg0, mb0, mg1, stats, mv);
    k_final  <<<NQ / 8, 256, 0, stream>>>(mv, mg1, mb1, stats, out);
}

// Round 19
// 228.267 us; speedup vs baseline: 1.0977x; 1.0328x over previous
//
#include <hip/hip_runtime.h>
#include <cstddef>
#include <cstdint>

#define B_ 4
#define N_ 16384
#define M_ 2048
#define C_ 128
#define NQ (B_*M_)         // 8192 queries
#define NSAMP 32
#define SAMP (NQ*NSAMP)    // 262144 samples
#define EPS_ 1e-5f
#define R2_ 9.0f

typedef short s8v  __attribute__((ext_vector_type(8)));
typedef float f32x4 __attribute__((ext_vector_type(4)));

// stats: 16 contention-split copies of a 1024-float block
#define ST_COPIES 16
#define ST_S0S 0
#define ST_S0Q 64
#define ST_S1S 128
#define ST_S1Q 136
#define ST_M1S 144
#define ST_M1Q 272
#define ST_M2S 400
#define ST_M2Q 656

__device__ __forceinline__ unsigned short f2bf(float f) {
    unsigned int u = __builtin_bit_cast(unsigned int, f);
    u += 0x7fffu + ((u >> 16) & 1u);     // round-to-nearest-even
    return (unsigned short)(u >> 16);
}
__device__ __forceinline__ float bf2f(unsigned short h) {
    unsigned int u = ((unsigned int)h) << 16;
    return __builtin_bit_cast(float, u);
}
__device__ __forceinline__ float fxor(float f, unsigned m) {
    return __builtin_bit_cast(float, __builtin_bit_cast(unsigned, f) ^ m);
}

// ---- merged head kernel: blocks [0,208) prep_w | [208,1232) transpose | [1232,1264) shift0
__global__ void __launch_bounds__(256)
k_head(const float* __restrict__ w0, const float* __restrict__ w1,
       unsigned short* __restrict__ w0p, unsigned short* __restrict__ w1p,
       const float* __restrict__ feat, unsigned short* __restrict__ featT,
       const float* __restrict__ xyz, const float* __restrict__ w0s,
       float* __restrict__ t0, float* __restrict__ stats) {
    __shared__ unsigned short tl[64][130];
    int bid = blockIdx.x, t = threadIdx.x;
    if (bid < 208) {
        int i = bid * 256 + t;
        const int tot0 = 128 * 160;
        if (i < tot0) {
            int o = i / 160, c = i - o * 160;
            float v = 0.f;
            if (c < 128)      v = w0[o * 131 + 3 + c];
            else if (c < 131) v = w0[o * 131 + (c - 128)];
            w0p[i] = f2bf(v);
        }
        int j = i - tot0;
        if (j >= 0 && j < 256 * 128) w1p[j] = f2bf(w1[j]);
    } else if (bid < 1232) {
        int tb = bid - 208;
        int b  = tb >> 8;
        int n0 = (tb & 255) * 64;
        const float* src = feat + (size_t)b * C_ * N_;
        for (int i = 0; i < 32; ++i) {
            int lin = i * 256 + t;
            int c = lin >> 6, n = lin & 63;
            tl[n][c] = f2bf(src[(size_t)c * N_ + n0 + n]);
        }
        __syncthreads();
        unsigned short* dst = featT + ((size_t)b * N_ + n0) * 128;
        #pragma unroll
        for (int i = 0; i < 4; ++i) {
            int lin = i * 256 + t;
            int n = lin >> 4, cg = lin & 15;
            s8v v;
            #pragma unroll
            for (int e = 0; e < 8; ++e) v[e] = (short)tl[n][cg*8 + e];
            *(s8v*)(dst + (size_t)n * 128 + cg * 8) = v;
        }
    } else {
        float* w  = (float*)&tl[0][0];
        float* ps = w + 192;
        float* pq = ps + 256;
        int wave = t >> 6, lane = t & 63;
        if (t < 192) w[t] = w0s[t];
        __syncthreads();
        int p = (bid - 1232) * 256 + t;
        float q0 = xyz[p*3], q1 = xyz[p*3+1], q2 = xyz[p*3+2];
        float* orow = t0 + (size_t)p * 64;
        #pragma unroll
        for (int o = 0; o < 64; ++o) {
            float v = w[3*o]*q0 + w[3*o+1]*q1 + w[3*o+2]*q2;
            orow[o] = v;
            float s = v, sq = v * v;
            #pragma unroll
            for (int mk = 32; mk; mk >>= 1) { s += __shfl_xor(s, mk); sq += __shfl_xor(sq, mk); }
            if (lane == 0) { ps[wave*64 + o] = s; pq[wave*64 + o] = sq; }
        }
        __syncthreads();
        if (t < 64) {
            float s = ps[t] + ps[64+t] + ps[128+t] + ps[192+t];
            float q = pq[t] + pq[64+t] + pq[128+t] + pq[192+t];
            atomicAdd(&stats[ST_S0S + t], s);
            atomicAdd(&stats[ST_S0Q + t], q);
        }
    }
}

// ---- shift layer 1
__global__ void k_shift1(const float* __restrict__ t0, const float* __restrict__ w1s,
                         const float* __restrict__ g0, const float* __restrict__ b0,
                         float* __restrict__ t1, float* __restrict__ stats) {
    __shared__ float aa[64], bb[64], wl[192];
    __shared__ float ps[4][3], pq[4][3];
    int t = threadIdx.x, wave = t >> 6, lane = t & 63;
    if (t < 64) {
        float mean = stats[ST_S0S + t] * (1.f / NQ);
        float var  = stats[ST_S0Q + t] * (1.f / NQ) - mean * mean;
        float a = g0[t] * rsqrtf(var + EPS_);
        aa[t] = a; bb[t] = b0[t] - mean * a;
    }
    if (t < 192) wl[t] = w1s[t];
    __syncthreads();
    int p = blockIdx.x * 256 + t;
    const f32x4* xr = (const f32x4*)(t0 + (size_t)p * 64);
    float v0 = 0.f, v1 = 0.f, v2 = 0.f;
    #pragma unroll
    for (int i = 0; i < 16; ++i) {
        f32x4 x = xr[i];
        #pragma unroll
        for (int j = 0; j < 4; ++j) {
            int c = 4*i + j;
            float h = fmaxf(0.f, aa[c] * x[j] + bb[c]);
            v0 += wl[c] * h; v1 += wl[64 + c] * h; v2 += wl[128 + c] * h;
        }
    }
    t1[p*3] = v0; t1[p*3+1] = v1; t1[p*3+2] = v2;
    float vv[3] = {v0, v1, v2};
    #pragma unroll
    for (int o = 0; o < 3; ++o) {
        float s = vv[o], q = vv[o] * vv[o];
        #pragma unroll
        for (int mk = 32; mk; mk >>= 1) { s += __shfl_xor(s, mk); q += __shfl_xor(q, mk); }
        if (lane == 0) { ps[wave][o] = s; pq[wave][o] = q; }
    }
    __syncthreads();
    if (t < 3) {
        float s = ps[0][t] + ps[1][t] + ps[2][t] + ps[3][t];
        float q = pq[0][t] + pq[1][t] + pq[2][t] + pq[3][t];
        atomicAdd(&stats[ST_S1S + t], s);
        atomicAdd(&stats[ST_S1Q + t], q);
    }
}

// ---- ball query v5: 256 blocks x 32 queries (8 per wave), LDS-chunked scan
__global__ void __launch_bounds__(256)
k_ballq(const float* __restrict__ bxyz, const float* __restrict__ t1,
        const float* __restrict__ g1, const float* __restrict__ b1,
        const float* __restrict__ stats, float* __restrict__ nxyz,
        int* __restrict__ idxb) {
    __shared__ float pts[4096 * 3];          // 48 KB
    int tid = threadIdx.x, wave = tid >> 6, lane = tid & 63;
    int b = blockIdx.x >> 6;                 // 64 blocks per batch
    int qbase = blockIdx.x * 32 + wave * 8;  // 8 queries per wave
    const float* bp = bxyz + (size_t)b * N_ * 3;
    unsigned long long below = (lane == 63) ? ~0ull >> 1 : ((1ull << lane) - 1ull);

    float av[3], bv[3];
    #pragma unroll
    for (int o = 0; o < 3; ++o) {
        float mean = stats[ST_S1S + o] * (1.f / NQ);
        float var  = stats[ST_S1Q + o] * (1.f / NQ) - mean * mean;
        float a = g1[o] * rsqrtf(var + EPS_);
        av[o] = a; bv[o] = b1[o] - mean * a;
    }
    float qx[8], qy[8], qz[8], sq[8];
    int cnt[8], first[8];
    #pragma unroll
    for (int q = 0; q < 8; ++q) {
        qx[q] = fmaxf(0.f, av[0] * t1[(qbase+q)*3]   + bv[0]);
        qy[q] = fmaxf(0.f, av[1] * t1[(qbase+q)*3+1] + bv[1]);
        qz[q] = fmaxf(0.f, av[2] * t1[(qbase+q)*3+2] + bv[2]);
        sq[q] = __fadd_rn(__fadd_rn(__fmul_rn(qx[q],qx[q]), __fmul_rn(qy[q],qy[q])), __fmul_rn(qz[q],qz[q]));
        cnt[q] = 0; first[q] = 0;
    }
    if (lane < 24) {
        int q = lane / 3, o = lane % 3;
        float ao = (o == 0) ? av[0] : ((o == 1) ? av[1] : av[2]);
        float bo = (o == 0) ? bv[0] : ((o == 1) ? bv[1] : bv[2]);
        nxyz[(qbase+q)*3 + o] = fmaxf(0.f, ao * t1[(qbase+q)*3 + o] + bo);
    }

    for (int ch = 0; ch < 4; ++ch) {
        __syncthreads();
        {
            const f32x4* src = (const f32x4*)(bp + ch * 12288);
            f32x4* d4 = (f32x4*)pts;
            #pragma unroll
            for (int i = 0; i < 12; ++i) d4[i*256 + tid] = src[i*256 + tid];
        }
        __syncthreads();
        #pragma unroll
        for (int q = 0; q < 8; ++q) {
            if (cnt[q] >= 32) continue;
            for (int j0 = 0; j0 < 4096 && cnt[q] < 32; j0 += 256) {
                #pragma unroll
                for (int u = 0; u < 4; ++u) {
                    if (cnt[q] < 32) {
                        int jl = j0 + u*64 + lane;
                        float x = pts[jl*3], y = pts[jl*3+1], z = pts[jl*3+2];
                        float sx  = __fadd_rn(__fadd_rn(__fmul_rn(x,x), __fmul_rn(y,y)), __fmul_rn(z,z));
                        float dot = __fadd_rn(__fadd_rn(__fmul_rn(qx[q],x), __fmul_rn(qy[q],y)), __fmul_rn(qz[q],z));
                        float d2  = __fsub_rn(__fadd_rn(sq[q], sx), __fmul_rn(2.0f, dot));
                        unsigned long long m = __ballot(d2 < R2_);
                        if (cnt[q] == 0 && m != 0ull)
                            first[q] = ch*4096 + j0 + u*64 + __ffsll((long long)m) - 1;
                        int pre = cnt[q] + __popcll(m & below);
                        if (((m >> lane) & 1ull) && pre < 32)
                            idxb[(size_t)(qbase+q)*32 + pre] = ch*4096 + jl;
                        cnt[q] += __popcll(m);
                    }
                }
            }
        }
    }
    #pragma unroll
    for (int q = 0; q < 8; ++q) {
        if (cnt[q] < 32) {
            int f = (cnt[q] == 0) ? 0 : first[q];
            for (int k = cnt[q] + lane; k < 32; k += 64) idxb[(size_t)(qbase+q)*32 + k] = f;
        }
    }
}

// ---- GEMM1 (QPB=4, grid 2048): FLIPPED, LDS-staged, 2 rounds of 2 queries, register prefetch.
__global__ void __launch_bounds__(256)
k_gemm1(const unsigned short* __restrict__ featT, const float* __restrict__ bxyz,
        const float* __restrict__ nxyz, const int* __restrict__ idxb,
        const unsigned short* __restrict__ w0p, unsigned short* __restrict__ y1,
        float* __restrict__ stats) {
    __shared__ unsigned short gt[64][168];
    __shared__ int pidx[128];
    __shared__ float nq[4][3];
    int tid  = threadIdx.x;
    int wave = tid >> 6, lane = tid & 63, quad = lane >> 4, l16 = lane & 15;
    int s2 = tid >> 2, part4 = tid & 3;
    int b = blockIdx.x >> 9;                 // 512 blocks per batch
    float* stc = stats + (size_t)(blockIdx.x & (ST_COPIES-1)) * 1024;

    s8v bfr[2][5];
    #pragma unroll
    for (int g = 0; g < 2; ++g)
        #pragma unroll
        for (int kk = 0; kk < 5; ++kk)
            bfr[g][kk] = *(const s8v*)(w0p + (wave*32 + g*16 + l16)*160 + kk*32 + quad*8);

    if (tid < 128) pidx[tid] = idxb[blockIdx.x * 128 + tid];
    if (tid < 12) nq[tid / 3][tid % 3] = nxyz[blockIdx.x * 12 + tid];
    if (tid < 64)
        for (int c = 131; c < 160; ++c) gt[tid][c] = 0;
    __syncthreads();

    s8v pv[4]; float prel0 = 0.f, prel1 = 0.f, prel2 = 0.f;
    {
        int pp = pidx[s2];
        const unsigned short* src = featT + ((size_t)(b * N_ + pp)) * 128 + part4 * 32;
        pv[0] = *(const s8v*)src;        pv[1] = *(const s8v*)(src + 8);
        pv[2] = *(const s8v*)(src + 16); pv[3] = *(const s8v*)(src + 24);
        if (tid < 64) {
            int pq_ = pidx[tid];
            const float* bx = bxyz + (size_t)(b * N_ + pq_) * 3;
            int q = tid >> 5;
            prel0 = bx[0] - nq[q][0]; prel1 = bx[1] - nq[q][1]; prel2 = bx[2] - nq[q][2];
        }
    }
    float csum[2] = {}, csq[2] = {};

    for (int r = 0; r < 2; ++r) {
        __syncthreads();
        *(s8v*)&gt[s2][part4*32]      = pv[0];
        *(s8v*)&gt[s2][part4*32 + 8]  = pv[1];
        *(s8v*)&gt[s2][part4*32 + 16] = pv[2];
        *(s8v*)&gt[s2][part4*32 + 24] = pv[3];
        if (tid < 64) {
            gt[tid][128] = f2bf(prel0); gt[tid][129] = f2bf(prel1); gt[tid][130] = f2bf(prel2);
        }
        if (r + 1 < 2) {
            int pp = pidx[64 + s2];
            const unsigned short* src = featT + ((size_t)(b * N_ + pp)) * 128 + part4 * 32;
            pv[0] = *(const s8v*)src;        pv[1] = *(const s8v*)(src + 8);
            pv[2] = *(const s8v*)(src + 16); pv[3] = *(const s8v*)(src + 24);
            if (tid < 64) {
                int pq_ = pidx[64 + tid];
                const float* bx = bxyz + (size_t)(b * N_ + pq_) * 3;
                int q = 2 + (tid >> 5);
                prel0 = bx[0] - nq[q][0]; prel1 = bx[1] - nq[q][1]; prel2 = bx[2] - nq[q][2];
            }
        }
        __syncthreads();
        f32x4 acc[2][4] = {};
        #pragma unroll
        for (int kk = 0; kk < 5; ++kk) {
            s8v at[4];
            #pragma unroll
            for (int t = 0; t < 4; ++t)
                at[t] = *(const s8v*)&gt[t*16 + l16][kk*32 + quad*8];
            #pragma unroll
            for (int g = 0; g < 2; ++g)
                #pragma unroll
                for (int t = 0; t < 4; ++t)
                    acc[g][t] = __builtin_amdgcn_mfma_f32_16x16x32_bf16(at[t], bfr[g][kk], acc[g][t], 0, 0, 0);
        }
        size_t sbase = (size_t)blockIdx.x * 128 + r * 64;
        #pragma unroll
        for (int g = 0; g < 2; ++g) {
            int ch = wave*32 + g*16 + l16;
            #pragma unroll
            for (int t = 0; t < 4; ++t)
                #pragma unroll
                for (int rr = 0; rr < 4; ++rr) {
                    float v = acc[g][t][rr];
                    y1[(sbase + t*16 + quad*4 + rr) * 128 + ch] = f2bf(v);
                    csum[g] += v; csq[g] += v * v;
                }
        }
    }
    #pragma unroll
    for (int g = 0; g < 2; ++g) {
        float s = csum[g], q = csq[g];
        s += __shfl_xor(s, 16); s += __shfl_xor(s, 32);
        q += __shfl_xor(q, 16); q += __shfl_xor(q, 32);
        if (quad == 0) {
            int ch = wave*32 + g*16 + l16;
            atomicAdd(&stc[ST_M1S + ch], s);
            atomicAdd(&stc[ST_M1Q + ch], q);
        }
    }
}

// ---- GEMM2 (QPB=4, grid 2048): single-stage (128 samples staged once, 1 barrier),
// 2 barrier-free MFMA rounds, sign-directed single reduction.
__global__ void __launch_bounds__(256)
k_gemm2(const unsigned short* __restrict__ y1, const unsigned short* __restrict__ w1p,
        const float* __restrict__ g1m, const float* __restrict__ b1m,
        const float* __restrict__ g2m,
        float* __restrict__ stats, float* __restrict__ mv) {
    __shared__ unsigned short ht[128][136];
    __shared__ float a1l[128], b1l[128];
    int tid = threadIdx.x;
    float* stc = stats + (size_t)(blockIdx.x & (ST_COPIES-1)) * 1024;
    if (tid < 128) {
        float ssum = 0.f, ssq = 0.f;
        #pragma unroll
        for (int c8 = 0; c8 < ST_COPIES; ++c8) {
            ssum += stats[c8*1024 + ST_M1S + tid];
            ssq  += stats[c8*1024 + ST_M1Q + tid];
        }
        float mean = ssum * (1.f / SAMP);
        float var  = ssq  * (1.f / SAMP) - mean * mean;
        float a = g1m[tid] * rsqrtf(var + EPS_);
        a1l[tid] = a; b1l[tid] = b1m[tid] - mean * a;
    }
    __syncthreads();
    int wave = tid >> 6, lane = tid & 63, quad = lane >> 4, l16 = lane & 15;
    int s = tid >> 3, part = tid & 7;

    float a1r[16], b1r[16];
    {
        const float* ap = &a1l[part * 16];
        const float* bp = &b1l[part * 16];
        #pragma unroll
        for (int i = 0; i < 16; ++i) { a1r[i] = ap[i]; b1r[i] = bp[i]; }
    }
    s8v bfr[4][4];
    unsigned fmask[4];
    #pragma unroll
    for (int g = 0; g < 4; ++g) {
        int c = wave*64 + g*16 + l16;
        fmask[g] = (g2m[c] >= 0.f) ? 0u : 0x80000000u;
        #pragma unroll
        for (int kk = 0; kk < 4; ++kk)
            bfr[g][kk] = *(const s8v*)(w1p + c*128 + kk*32 + quad*8);
    }

    size_t base = (size_t)blockIdx.x * 128;
    s8v rv[4][2];
    #pragma unroll
    for (int q = 0; q < 4; ++q) {
        const unsigned short* src = y1 + (base + q*32 + s) * 128 + part * 16;
        rv[q][0] = *(const s8v*)src; rv[q][1] = *(const s8v*)(src + 8);
    }
    #pragma unroll
    for (int q = 0; q < 4; ++q) {
        s8v o0, o1;
        #pragma unroll
        for (int e = 0; e < 8; ++e) {
            float f0 = bf2f((unsigned short)rv[q][0][e]);
            float f1 = bf2f((unsigned short)rv[q][1][e]);
            o0[e] = (short)f2bf(fmaxf(0.f, a1r[e]     * f0 + b1r[e]));
            o1[e] = (short)f2bf(fmaxf(0.f, a1r[8 + e] * f1 + b1r[8 + e]));
        }
        *(s8v*)&ht[q*32 + s][part*16]     = o0;
        *(s8v*)&ht[q*32 + s][part*16 + 8] = o1;
    }
    __syncthreads();   // the only in-loop barrier

    float csum[4] = {}, csq[4] = {};
    for (int r = 0; r < 2; ++r) {
        f32x4 acc[4][4] = {};
        #pragma unroll
        for (int kk = 0; kk < 4; ++kk) {
            s8v at[4];
            #pragma unroll
            for (int t = 0; t < 4; ++t)
                at[t] = *(const s8v*)&ht[r*64 + t*16 + l16][kk*32 + quad*8];
            #pragma unroll
            for (int g = 0; g < 4; ++g)
                #pragma unroll
                for (int t = 0; t < 4; ++t)
                    acc[g][t] = __builtin_amdgcn_mfma_f32_16x16x32_bf16(at[t], bfr[g][kk], acc[g][t], 0, 0, 0);
        }
        #pragma unroll
        for (int g = 0; g < 4; ++g) {
            float sacc = 0.f, qacc = 0.f;
            #pragma unroll
            for (int t = 0; t < 4; ++t)
                #pragma unroll
                for (int e = 0; e < 4; ++e) {
                    float v = acc[g][t][e];
                    sacc += v; qacc = __builtin_fmaf(v, v, qacc);
                }
            csum[g] += sacc; csq[g] += qacc;
            #pragma unroll
            for (int qh = 0; qh < 2; ++qh) {
                int gq = blockIdx.x * 4 + r*2 + qh;
                f32x4 v0 = acc[g][2*qh], v1 = acc[g][2*qh + 1];
                float m = fxor(v0[0], fmask[g]);
                #pragma unroll
                for (int e = 1; e < 4; ++e) m = fmaxf(m, fxor(v0[e], fmask[g]));
                #pragma unroll
                for (int e = 0; e < 4; ++e) m = fmaxf(m, fxor(v1[e], fmask[g]));
                m = fmaxf(m, __shfl_xor(m, 16));
                m = fmaxf(m, __shfl_xor(m, 32));
                if (quad == 0) {
                    int c = wave*64 + g*16 + l16;
                    mv[(size_t)gq * 256 + c] = fxor(m, fmask[g]);
                }
            }
        }
    }
    #pragma unroll
    for (int g = 0; g < 4; ++g) {
        float sv = csum[g], q = csq[g];
        sv += __shfl_xor(sv, 16); sv += __shfl_xor(sv, 32);
        q  += __shfl_xor(q, 16);  q  += __shfl_xor(q, 32);
        if (quad == 0) {
            int c = wave*64 + g*16 + l16;
            atomicAdd(&stc[ST_M2S + c], sv);
            atomicAdd(&stc[ST_M2Q + c], q);
        }
    }
}

// ---- epilogue (bn2 folded in): out = relu(a2 * mv + b2); grid 1024 x 8 rows
__global__ void k_final(const float* __restrict__ mv, const float* __restrict__ g2m,
                        const float* __restrict__ b2m, const float* __restrict__ stats,
                        float* __restrict__ out) {
    __shared__ float ab[512];
    int tid = threadIdx.x;
    {
        float ssum = 0.f, ssq = 0.f;
        #pragma unroll
        for (int c8 = 0; c8 < ST_COPIES; ++c8) {
            ssum += stats[c8*1024 + ST_M2S + tid];
            ssq  += stats[c8*1024 + ST_M2Q + tid];
        }
        float mean = ssum * (1.f / SAMP);
        float var  = ssq  * (1.f / SAMP) - mean * mean;
        float a = g2m[tid] * rsqrtf(var + EPS_);
        ab[tid] = a; ab[256 + tid] = b2m[tid] - mean * a;
    }
    __syncthreads();
    size_t base = (size_t)blockIdx.x * 2048;
    float a = ab[tid], bb = ab[256 + tid];
    #pragma unroll
    for (int k = 0; k < 8; ++k) {
        size_t i = base + k*256 + tid;
        out[i] = fmaxf(0.f, a * mv[i] + bb);
    }
}

extern "C" void kernel_launch(void* const* d_in, const int* in_sizes, int n_in,
                              void* d_out, int out_size, void* d_ws, size_t ws_size,
                              hipStream_t stream) {
    const float* ffps = (const float*)d_in[0];
    const float* bxyz = (const float*)d_in[1];
    const float* feat = (const float*)d_in[2];
    const float* sw0  = (const float*)d_in[3];
    const float* sg0  = (const float*)d_in[4];
    const float* sb0  = (const float*)d_in[5];
    const float* sw1  = (const float*)d_in[6];
    const float* sg1  = (const float*)d_in[7];
    const float* sb1  = (const float*)d_in[8];
    const float* mw0  = (const float*)d_in[9];
    const float* mg0  = (const float*)d_in[10];
    const float* mb0  = (const float*)d_in[11];
    const float* mw1  = (const float*)d_in[12];
    const float* mg1  = (const float*)d_in[13];
    const float* mb1  = (const float*)d_in[14];
    float* out = (float*)d_out;

    char* ws = (char*)d_ws;
    size_t off = 0;
    auto alloc = [&](size_t bytes) -> void* {
        void* p = ws + off;
        off += (bytes + 255) & ~(size_t)255;
        return p;
    };
    float*          stats = (float*)alloc(ST_COPIES * 1024 * 4);
    float*          t0    = (float*)alloc((size_t)NQ * 64 * 4);
    float*          t1    = (float*)alloc((size_t)NQ * 3 * 4);
    float*          nxyz  = (float*)alloc((size_t)NQ * 3 * 4);
    int*            idxb  = (int*)alloc((size_t)NQ * 32 * 4);
    unsigned short* w0p   = (unsigned short*)alloc(128 * 160 * 2);
    unsigned short* w1p   = (unsigned short*)alloc(256 * 128 * 2);
    unsigned short* featT = (unsigned short*)alloc((size_t)B_ * N_ * 128 * 2);
    unsigned short* y1    = (unsigned short*)alloc((size_t)SAMP * 128 * 2);
    float*          mv    = (float*)alloc((size_t)NQ * 256 * 4);
    (void)in_sizes; (void)n_in; (void)out_size; (void)ws_size;

    hipMemsetAsync(stats, 0, ST_COPIES * 1024 * 4, stream);
    k_head   <<<1264, 256, 0, stream>>>(mw0, mw1, w0p, w1p, feat, featT, ffps, sw0, t0, stats);
    k_shift1 <<<NQ / 256, 256, 0, stream>>>(t0, sw1, sg0, sb0, t1, stats);
    k_ballq  <<<NQ / 32, 256, 0, stream>>>(bxyz, t1, sg1, sb1, stats, nxyz, idxb);
    k_gemm1  <<<NQ / 4, 256, 0, stream>>>(featT, bxyz, nxyz, idxb, w0p, y1, stats);
    k_gemm2  <<<NQ / 4, 256, 0, stream>>>(y1, w1p, mg0, mb0, mg1, stats, mv);
    k_final  <<<NQ / 8, 256, 0, stream>>>(mv, mg1, mb1, stats, out);
}

// Round 20
// 221.587 us; speedup vs baseline: 1.1308x; 1.0301x over previous
//
#include <hip/hip_runtime.h>
#include <cstddef>
#include <cstdint>

#define B_ 4
#define N_ 16384
#define M_ 2048
#define C_ 128
#define NQ (B_*M_)         // 8192 queries
#define NSAMP 32
#define SAMP (NQ*NSAMP)    // 262144 samples
#define EPS_ 1e-5f
#define R2_ 9.0f

typedef short s8v  __attribute__((ext_vector_type(8)));
typedef float f32x4 __attribute__((ext_vector_type(4)));

// stats layout (floats):
//  [STS0, STS0+4096)  : 32 shift0 slots x 128 (sum[64]@+0, sq[64]@+64)  -- pure writes
//  [STS1, STS1+256)   : 32 shift1 slots x 8   (sum[3]@+0, sq[3]@+4)     -- pure writes
//  [STMC, STMC+16384) : 16 contention-split copies x 1024
//                       per copy: M1S@0, M1Q@128, M2S@256, M2Q@512      -- atomics (zeroed in k_head)
#define STS0 0
#define STS1 4096
#define STMC 4608
#define ST_COPIES 16

__device__ __forceinline__ unsigned short f2bf(float f) {
    unsigned int u = __builtin_bit_cast(unsigned int, f);
    u += 0x7fffu + ((u >> 16) & 1u);     // round-to-nearest-even
    return (unsigned short)(u >> 16);
}
__device__ __forceinline__ float bf2f(unsigned short h) {
    unsigned int u = ((unsigned int)h) << 16;
    return __builtin_bit_cast(float, u);
}
__device__ __forceinline__ float fxor(float f, unsigned m) {
    return __builtin_bit_cast(float, __builtin_bit_cast(unsigned, f) ^ m);
}

// ---- merged head: [0,208) prep_w | [208,1232) transpose | [1232,1264) shift0 | [1264,1328) zero MC
__global__ void __launch_bounds__(256)
k_head(const float* __restrict__ w0, const float* __restrict__ w1,
       unsigned short* __restrict__ w0p, unsigned short* __restrict__ w1p,
       const float* __restrict__ feat, unsigned short* __restrict__ featT,
       const float* __restrict__ xyz, const float* __restrict__ w0s,
       float* __restrict__ t0, float* __restrict__ stats) {
    __shared__ unsigned short tl[64][130];
    int bid = blockIdx.x, t = threadIdx.x;
    if (bid < 208) {
        int i = bid * 256 + t;
        const int tot0 = 128 * 160;
        if (i < tot0) {
            int o = i / 160, c = i - o * 160;
            float v = 0.f;
            if (c < 128)      v = w0[o * 131 + 3 + c];
            else if (c < 131) v = w0[o * 131 + (c - 128)];
            w0p[i] = f2bf(v);
        }
        int j = i - tot0;
        if (j >= 0 && j < 256 * 128) w1p[j] = f2bf(w1[j]);
    } else if (bid < 1232) {
        int tb = bid - 208;
        int b  = tb >> 8;
        int n0 = (tb & 255) * 64;
        const float* src = feat + (size_t)b * C_ * N_;
        for (int i = 0; i < 32; ++i) {
            int lin = i * 256 + t;
            int c = lin >> 6, n = lin & 63;
            tl[n][c] = f2bf(src[(size_t)c * N_ + n0 + n]);
        }
        __syncthreads();
        unsigned short* dst = featT + ((size_t)b * N_ + n0) * 128;
        #pragma unroll
        for (int i = 0; i < 4; ++i) {
            int lin = i * 256 + t;
            int n = lin >> 4, cg = lin & 15;
            s8v v;
            #pragma unroll
            for (int e = 0; e < 8; ++e) v[e] = (short)tl[n][cg*8 + e];
            *(s8v*)(dst + (size_t)n * 128 + cg * 8) = v;
        }
    } else if (bid < 1264) {
        // shift0: 32 blocks, per-block slot write (no atomics)
        float* w  = (float*)&tl[0][0];
        float* ps = w + 192;
        float* pq = ps + 256;
        int wave = t >> 6, lane = t & 63;
        int sb = bid - 1232;
        if (t < 192) w[t] = w0s[t];
        __syncthreads();
        int p = sb * 256 + t;
        float q0 = xyz[p*3], q1 = xyz[p*3+1], q2 = xyz[p*3+2];
        float* orow = t0 + (size_t)p * 64;
        #pragma unroll
        for (int o = 0; o < 64; ++o) {
            float v = w[3*o]*q0 + w[3*o+1]*q1 + w[3*o+2]*q2;
            orow[o] = v;
            float s = v, sq = v * v;
            #pragma unroll
            for (int mk = 32; mk; mk >>= 1) { s += __shfl_xor(s, mk); sq += __shfl_xor(sq, mk); }
            if (lane == 0) { ps[wave*64 + o] = s; pq[wave*64 + o] = sq; }
        }
        __syncthreads();
        if (t < 64) {
            stats[STS0 + sb*128 + t]      = ps[t] + ps[64+t] + ps[128+t] + ps[192+t];
            stats[STS0 + sb*128 + 64 + t] = pq[t] + pq[64+t] + pq[128+t] + pq[192+t];
        }
    } else {
        // zero the 16 atomic stat copies (64 blocks x 256 = 16384 floats)
        stats[STMC + (bid - 1264) * 256 + t] = 0.f;
    }
}

// ---- shift layer 1: sums 32 shift0 slots; writes its own shift1 slot (no atomics)
__global__ void k_shift1(const float* __restrict__ t0, const float* __restrict__ w1s,
                         const float* __restrict__ g0, const float* __restrict__ b0,
                         float* __restrict__ t1, float* __restrict__ stats) {
    __shared__ float aa[64], bb[64], wl[192];
    __shared__ float ps[4][3], pq[4][3];
    int t = threadIdx.x, wave = t >> 6, lane = t & 63;
    if (t < 64) {
        float ssum = 0.f, ssq = 0.f;
        for (int i = 0; i < 32; ++i) {
            ssum += stats[STS0 + i*128 + t];
            ssq  += stats[STS0 + i*128 + 64 + t];
        }
        float mean = ssum * (1.f / NQ);
        float var  = ssq  * (1.f / NQ) - mean * mean;
        float a = g0[t] * rsqrtf(var + EPS_);
        aa[t] = a; bb[t] = b0[t] - mean * a;
    }
    if (t < 192) wl[t] = w1s[t];
    __syncthreads();
    int p = blockIdx.x * 256 + t;
    const f32x4* xr = (const f32x4*)(t0 + (size_t)p * 64);
    float v0 = 0.f, v1 = 0.f, v2 = 0.f;
    #pragma unroll
    for (int i = 0; i < 16; ++i) {
        f32x4 x = xr[i];
        #pragma unroll
        for (int j = 0; j < 4; ++j) {
            int c = 4*i + j;
            float h = fmaxf(0.f, aa[c] * x[j] + bb[c]);
            v0 += wl[c] * h; v1 += wl[64 + c] * h; v2 += wl[128 + c] * h;
        }
    }
    t1[p*3] = v0; t1[p*3+1] = v1; t1[p*3+2] = v2;
    float vv[3] = {v0, v1, v2};
    #pragma unroll
    for (int o = 0; o < 3; ++o) {
        float s = vv[o], q = vv[o] * vv[o];
        #pragma unroll
        for (int mk = 32; mk; mk >>= 1) { s += __shfl_xor(s, mk); q += __shfl_xor(q, mk); }
        if (lane == 0) { ps[wave][o] = s; pq[wave][o] = q; }
    }
    __syncthreads();
    if (t < 3) {
        stats[STS1 + blockIdx.x*8 + t]     = ps[0][t] + ps[1][t] + ps[2][t] + ps[3][t];
        stats[STS1 + blockIdx.x*8 + 4 + t] = pq[0][t] + pq[1][t] + pq[2][t] + pq[3][t];
    }
}

// ---- ball query v5: 256 blocks x 32 queries (8 per wave), LDS-chunked scan
__global__ void __launch_bounds__(256)
k_ballq(const float* __restrict__ bxyz, const float* __restrict__ t1,
        const float* __restrict__ g1, const float* __restrict__ b1,
        const float* __restrict__ stats, float* __restrict__ nxyz,
        int* __restrict__ idxb) {
    __shared__ float pts[4096 * 3];          // 48 KB
    int tid = threadIdx.x, wave = tid >> 6, lane = tid & 63;
    int b = blockIdx.x >> 6;                 // 64 blocks per batch
    int qbase = blockIdx.x * 32 + wave * 8;  // 8 queries per wave
    const float* bp = bxyz + (size_t)b * N_ * 3;
    unsigned long long below = (lane == 63) ? ~0ull >> 1 : ((1ull << lane) - 1ull);

    float av[3], bv[3];
    #pragma unroll
    for (int o = 0; o < 3; ++o) {
        float ssum = 0.f, ssq = 0.f;
        for (int i = 0; i < 32; ++i) {
            ssum += stats[STS1 + i*8 + o];
            ssq  += stats[STS1 + i*8 + 4 + o];
        }
        float mean = ssum * (1.f / NQ);
        float var  = ssq  * (1.f / NQ) - mean * mean;
        float a = g1[o] * rsqrtf(var + EPS_);
        av[o] = a; bv[o] = b1[o] - mean * a;
    }
    float qx[8], qy[8], qz[8], sq[8];
    int cnt[8], first[8];
    #pragma unroll
    for (int q = 0; q < 8; ++q) {
        qx[q] = fmaxf(0.f, av[0] * t1[(qbase+q)*3]   + bv[0]);
        qy[q] = fmaxf(0.f, av[1] * t1[(qbase+q)*3+1] + bv[1]);
        qz[q] = fmaxf(0.f, av[2] * t1[(qbase+q)*3+2] + bv[2]);
        sq[q] = __fadd_rn(__fadd_rn(__fmul_rn(qx[q],qx[q]), __fmul_rn(qy[q],qy[q])), __fmul_rn(qz[q],qz[q]));
        cnt[q] = 0; first[q] = 0;
    }
    if (lane < 24) {
        int q = lane / 3, o = lane % 3;
        float ao = (o == 0) ? av[0] : ((o == 1) ? av[1] : av[2]);
        float bo = (o == 0) ? bv[0] : ((o == 1) ? bv[1] : bv[2]);
        nxyz[(qbase+q)*3 + o] = fmaxf(0.f, ao * t1[(qbase+q)*3 + o] + bo);
    }

    for (int ch = 0; ch < 4; ++ch) {
        __syncthreads();
        {
            const f32x4* src = (const f32x4*)(bp + ch * 12288);
            f32x4* d4 = (f32x4*)pts;
            #pragma unroll
            for (int i = 0; i < 12; ++i) d4[i*256 + tid] = src[i*256 + tid];
        }
        __syncthreads();
        #pragma unroll
        for (int q = 0; q < 8; ++q) {
            if (cnt[q] >= 32) continue;
            for (int j0 = 0; j0 < 4096 && cnt[q] < 32; j0 += 256) {
                #pragma unroll
                for (int u = 0; u < 4; ++u) {
                    if (cnt[q] < 32) {
                        int jl = j0 + u*64 + lane;
                        float x = pts[jl*3], y = pts[jl*3+1], z = pts[jl*3+2];
                        float sx  = __fadd_rn(__fadd_rn(__fmul_rn(x,x), __fmul_rn(y,y)), __fmul_rn(z,z));
                        float dot = __fadd_rn(__fadd_rn(__fmul_rn(qx[q],x), __fmul_rn(qy[q],y)), __fmul_rn(qz[q],z));
                        float d2  = __fsub_rn(__fadd_rn(sq[q], sx), __fmul_rn(2.0f, dot));
                        unsigned long long m = __ballot(d2 < R2_);
                        if (cnt[q] == 0 && m != 0ull)
                            first[q] = ch*4096 + j0 + u*64 + __ffsll((long long)m) - 1;
                        int pre = cnt[q] + __popcll(m & below);
                        if (((m >> lane) & 1ull) && pre < 32)
                            idxb[(size_t)(qbase+q)*32 + pre] = ch*4096 + jl;
                        cnt[q] += __popcll(m);
                    }
                }
            }
        }
    }
    #pragma unroll
    for (int q = 0; q < 8; ++q) {
        if (cnt[q] < 32) {
            int f = (cnt[q] == 0) ? 0 : first[q];
            for (int k = cnt[q] + lane; k < 32; k += 64) idxb[(size_t)(qbase+q)*32 + k] = f;
        }
    }
}

// ---- GEMM1 (QPB=4, grid 2048): FLIPPED, LDS-staged, 2 rounds of 2 queries, register prefetch.
__global__ void __launch_bounds__(256)
k_gemm1(const unsigned short* __restrict__ featT, const float* __restrict__ bxyz,
        const float* __restrict__ nxyz, const int* __restrict__ idxb,
        const unsigned short* __restrict__ w0p, unsigned short* __restrict__ y1,
        float* __restrict__ stats) {
    __shared__ unsigned short gt[64][168];
    __shared__ int pidx[128];
    __shared__ float nq[4][3];
    int tid  = threadIdx.x;
    int wave = tid >> 6, lane = tid & 63, quad = lane >> 4, l16 = lane & 15;
    int s2 = tid >> 2, part4 = tid & 3;
    int b = blockIdx.x >> 9;                 // 512 blocks per batch
    float* stc = stats + STMC + (size_t)(blockIdx.x & (ST_COPIES-1)) * 1024;

    s8v bfr[2][5];
    #pragma unroll
    for (int g = 0; g < 2; ++g)
        #pragma unroll
        for (int kk = 0; kk < 5; ++kk)
            bfr[g][kk] = *(const s8v*)(w0p + (wave*32 + g*16 + l16)*160 + kk*32 + quad*8);

    if (tid < 128) pidx[tid] = idxb[blockIdx.x * 128 + tid];
    if (tid < 12) nq[tid / 3][tid % 3] = nxyz[blockIdx.x * 12 + tid];
    if (tid < 64)
        for (int c = 131; c < 160; ++c) gt[tid][c] = 0;
    __syncthreads();

    s8v pv[4]; float prel0 = 0.f, prel1 = 0.f, prel2 = 0.f;
    {
        int pp = pidx[s2];
        const unsigned short* src = featT + ((size_t)(b * N_ + pp)) * 128 + part4 * 32;
        pv[0] = *(const s8v*)src;        pv[1] = *(const s8v*)(src + 8);
        pv[2] = *(const s8v*)(src + 16); pv[3] = *(const s8v*)(src + 24);
        if (tid < 64) {
            int pq_ = pidx[tid];
            const float* bx = bxyz + (size_t)(b * N_ + pq_) * 3;
            int q = tid >> 5;
            prel0 = bx[0] - nq[q][0]; prel1 = bx[1] - nq[q][1]; prel2 = bx[2] - nq[q][2];
        }
    }
    float csum[2] = {}, csq[2] = {};

    for (int r = 0; r < 2; ++r) {
        __syncthreads();
        *(s8v*)&gt[s2][part4*32]      = pv[0];
        *(s8v*)&gt[s2][part4*32 + 8]  = pv[1];
        *(s8v*)&gt[s2][part4*32 + 16] = pv[2];
        *(s8v*)&gt[s2][part4*32 + 24] = pv[3];
        if (tid < 64) {
            gt[tid][128] = f2bf(prel0); gt[tid][129] = f2bf(prel1); gt[tid][130] = f2bf(prel2);
        }
        if (r + 1 < 2) {
            int pp = pidx[64 + s2];
            const unsigned short* src = featT + ((size_t)(b * N_ + pp)) * 128 + part4 * 32;
            pv[0] = *(const s8v*)src;        pv[1] = *(const s8v*)(src + 8);
            pv[2] = *(const s8v*)(src + 16); pv[3] = *(const s8v*)(src + 24);
            if (tid < 64) {
                int pq_ = pidx[64 + tid];
                const float* bx = bxyz + (size_t)(b * N_ + pq_) * 3;
                int q = 2 + (tid >> 5);
                prel0 = bx[0] - nq[q][0]; prel1 = bx[1] - nq[q][1]; prel2 = bx[2] - nq[q][2];
            }
        }
        __syncthreads();
        f32x4 acc[2][4] = {};
        #pragma unroll
        for (int kk = 0; kk < 5; ++kk) {
            s8v at[4];
            #pragma unroll
            for (int t = 0; t < 4; ++t)
                at[t] = *(const s8v*)&gt[t*16 + l16][kk*32 + quad*8];
            #pragma unroll
            for (int g = 0; g < 2; ++g)
                #pragma unroll
                for (int t = 0; t < 4; ++t)
                    acc[g][t] = __builtin_amdgcn_mfma_f32_16x16x32_bf16(at[t], bfr[g][kk], acc[g][t], 0, 0, 0);
        }
        size_t sbase = (size_t)blockIdx.x * 128 + r * 64;
        #pragma unroll
        for (int g = 0; g < 2; ++g) {
            int ch = wave*32 + g*16 + l16;
            #pragma unroll
            for (int t = 0; t < 4; ++t)
                #pragma unroll
                for (int rr = 0; rr < 4; ++rr) {
                    float v = acc[g][t][rr];
                    y1[(sbase + t*16 + quad*4 + rr) * 128 + ch] = f2bf(v);
                    csum[g] += v; csq[g] += v * v;
                }
        }
    }
    #pragma unroll
    for (int g = 0; g < 2; ++g) {
        float s = csum[g], q = csq[g];
        s += __shfl_xor(s, 16); s += __shfl_xor(s, 32);
        q += __shfl_xor(q, 16); q += __shfl_xor(q, 32);
        if (quad == 0) {
            int ch = wave*32 + g*16 + l16;
            atomicAdd(&stc[ch], s);          // M1S
            atomicAdd(&stc[128 + ch], q);    // M1Q
        }
    }
}

// ---- GEMM2 (QPB=4, grid 2048): single-stage, 1 in-loop barrier, sign-directed reduction.
__global__ void __launch_bounds__(256)
k_gemm2(const unsigned short* __restrict__ y1, const unsigned short* __restrict__ w1p,
        const float* __restrict__ g1m, const float* __restrict__ b1m,
        const float* __restrict__ g2m,
        float* __restrict__ stats, float* __restrict__ mv) {
    __shared__ unsigned short ht[128][136];
    __shared__ float a1l[128], b1l[128];
    int tid = threadIdx.x;
    float* stc = stats + STMC + (size_t)(blockIdx.x & (ST_COPIES-1)) * 1024;
    if (tid < 128) {
        float ssum = 0.f, ssq = 0.f;
        #pragma unroll
        for (int c8 = 0; c8 < ST_COPIES; ++c8) {
            ssum += stats[STMC + c8*1024 + tid];         // M1S
            ssq  += stats[STMC + c8*1024 + 128 + tid];   // M1Q
        }
        float mean = ssum * (1.f / SAMP);
        float var  = ssq  * (1.f / SAMP) - mean * mean;
        float a = g1m[tid] * rsqrtf(var + EPS_);
        a1l[tid] = a; b1l[tid] = b1m[tid] - mean * a;
    }
    __syncthreads();
    int wave = tid >> 6, lane = tid & 63, quad = lane >> 4, l16 = lane & 15;
    int s = tid >> 3, part = tid & 7;

    float a1r[16], b1r[16];
    {
        const float* ap = &a1l[part * 16];
        const float* bp = &b1l[part * 16];
        #pragma unroll
        for (int i = 0; i < 16; ++i) { a1r[i] = ap[i]; b1r[i] = bp[i]; }
    }
    s8v bfr[4][4];
    unsigned fmask[4];
    #pragma unroll
    for (int g = 0; g < 4; ++g) {
        int c = wave*64 + g*16 + l16;
        fmask[g] = (g2m[c] >= 0.f) ? 0u : 0x80000000u;
        #pragma unroll
        for (int kk = 0; kk < 4; ++kk)
            bfr[g][kk] = *(const s8v*)(w1p + c*128 + kk*32 + quad*8);
    }

    size_t base = (size_t)blockIdx.x * 128;
    s8v rv[4][2];
    #pragma unroll
    for (int q = 0; q < 4; ++q) {
        const unsigned short* src = y1 + (base + q*32 + s) * 128 + part * 16;
        rv[q][0] = *(const s8v*)src; rv[q][1] = *(const s8v*)(src + 8);
    }
    #pragma unroll
    for (int q = 0; q < 4; ++q) {
        s8v o0, o1;
        #pragma unroll
        for (int e = 0; e < 8; ++e) {
            float f0 = bf2f((unsigned short)rv[q][0][e]);
            float f1 = bf2f((unsigned short)rv[q][1][e]);
            o0[e] = (short)f2bf(fmaxf(0.f, a1r[e]     * f0 + b1r[e]));
            o1[e] = (short)f2bf(fmaxf(0.f, a1r[8 + e] * f1 + b1r[8 + e]));
        }
        *(s8v*)&ht[q*32 + s][part*16]     = o0;
        *(s8v*)&ht[q*32 + s][part*16 + 8] = o1;
    }
    __syncthreads();   // the only in-loop barrier

    float csum[4] = {}, csq[4] = {};
    for (int r = 0; r < 2; ++r) {
        f32x4 acc[4][4] = {};
        #pragma unroll
        for (int kk = 0; kk < 4; ++kk) {
            s8v at[4];
            #pragma unroll
            for (int t = 0; t < 4; ++t)
                at[t] = *(const s8v*)&ht[r*64 + t*16 + l16][kk*32 + quad*8];
            #pragma unroll
            for (int g = 0; g < 4; ++g)
                #pragma unroll
                for (int t = 0; t < 4; ++t)
                    acc[g][t] = __builtin_amdgcn_mfma_f32_16x16x32_bf16(at[t], bfr[g][kk], acc[g][t], 0, 0, 0);
        }
        #pragma unroll
        for (int g = 0; g < 4; ++g) {
            float sacc = 0.f, qacc = 0.f;
            #pragma unroll
            for (int t = 0; t < 4; ++t)
                #pragma unroll
                for (int e = 0; e < 4; ++e) {
                    float v = acc[g][t][e];
                    sacc += v; qacc = __builtin_fmaf(v, v, qacc);
                }
            csum[g] += sacc; csq[g] += qacc;
            #pragma unroll
            for (int qh = 0; qh < 2; ++qh) {
                int gq = blockIdx.x * 4 + r*2 + qh;
                f32x4 v0 = acc[g][2*qh], v1 = acc[g][2*qh + 1];
                float m = fxor(v0[0], fmask[g]);
                #pragma unroll
                for (int e = 1; e < 4; ++e) m = fmaxf(m, fxor(v0[e], fmask[g]));
                #pragma unroll
                for (int e = 0; e < 4; ++e) m = fmaxf(m, fxor(v1[e], fmask[g]));
                m = fmaxf(m, __shfl_xor(m, 16));
                m = fmaxf(m, __shfl_xor(m, 32));
                if (quad == 0) {
                    int c = wave*64 + g*16 + l16;
                    mv[(size_t)gq * 256 + c] = fxor(m, fmask[g]);
                }
            }
        }
    }
    #pragma unroll
    for (int g = 0; g < 4; ++g) {
        float sv = csum[g], q = csq[g];
        sv += __shfl_xor(sv, 16); sv += __shfl_xor(sv, 32);
        q  += __shfl_xor(q, 16);  q  += __shfl_xor(q, 32);
        if (quad == 0) {
            int c = wave*64 + g*16 + l16;
            atomicAdd(&stc[256 + c], sv);   // M2S
            atomicAdd(&stc[512 + c], q);    // M2Q
        }
    }
}

// ---- epilogue (bn2 folded in): out = relu(a2 * mv + b2); grid 1024 x 8 rows
__global__ void k_final(const float* __restrict__ mv, const float* __restrict__ g2m,
                        const float* __restrict__ b2m, const float* __restrict__ stats,
                        float* __restrict__ out) {
    __shared__ float ab[512];
    int tid = threadIdx.x;
    {
        float ssum = 0.f, ssq = 0.f;
        #pragma unroll
        for (int c8 = 0; c8 < ST_COPIES; ++c8) {
            ssum += stats[STMC + c8*1024 + 256 + tid];   // M2S
            ssq  += stats[STMC + c8*1024 + 512 + tid];   // M2Q
        }
        float mean = ssum * (1.f / SAMP);
        float var  = ssq  * (1.f / SAMP) - mean * mean;
        float a = g2m[tid] * rsqrtf(var + EPS_);
        ab[tid] = a; ab[256 + tid] = b2m[tid] - mean * a;
    }
    __syncthreads();
    size_t base = (size_t)blockIdx.x * 2048;
    float a = ab[tid], bb = ab[256 + tid];
    #pragma unroll
    for (int k = 0; k < 8; ++k) {
        size_t i = base + k*256 + tid;
        out[i] = fmaxf(0.f, a * mv[i] + bb);
    }
}

extern "C" void kernel_launch(void* const* d_in, const int* in_sizes, int n_in,
                              void* d_out, int out_size, void* d_ws, size_t ws_size,
                              hipStream_t stream) {
    const float* ffps = (const float*)d_in[0];
    const float* bxyz = (const float*)d_in[1];
    const float* feat = (const float*)d_in[2];
    const float* sw0  = (const float*)d_in[3];
    const float* sg0  = (const float*)d_in[4];
    const float* sb0  = (const float*)d_in[5];
    const float* sw1  = (const float*)d_in[6];
    const float* sg1  = (const float*)d_in[7];
    const float* sb1  = (const float*)d_in[8];
    const float* mw0  = (const float*)d_in[9];
    const float* mg0  = (const float*)d_in[10];
    const float* mb0  = (const float*)d_in[11];
    const float* mw1  = (const float*)d_in[12];
    const float* mg1  = (const float*)d_in[13];
    const float* mb1  = (const float*)d_in[14];
    float* out = (float*)d_out;

    char* ws = (char*)d_ws;
    size_t off = 0;
    auto alloc = [&](size_t bytes) -> void* {
        void* p = ws + off;
        off += (bytes + 255) & ~(size_t)255;
        return p;
    };
    float*          stats = (float*)alloc((STMC + ST_COPIES * 1024) * 4);
    float*          t0    = (float*)alloc((size_t)NQ * 64 * 4);
    float*          t1    = (float*)alloc((size_t)NQ * 3 * 4);
    float*          nxyz  = (float*)alloc((size_t)NQ * 3 * 4);
    int*            idxb  = (int*)alloc((size_t)NQ * 32 * 4);
    unsigned short* w0p   = (unsigned short*)alloc(128 * 160 * 2);
    unsigned short* w1p   = (unsigned short*)alloc(256 * 128 * 2);
    unsigned short* featT = (unsigned short*)alloc((size_t)B_ * N_ * 128 * 2);
    unsigned short* y1    = (unsigned short*)alloc((size_t)SAMP * 128 * 2);
    float*          mv    = (float*)alloc((size_t)NQ * 256 * 4);
    (void)in_sizes; (void)n_in; (void)out_size; (void)ws_size;

    k_head   <<<1328, 256, 0, stream>>>(mw0, mw1, w0p, w1p, feat, featT, ffps, sw0, t0, stats);
    k_shift1 <<<NQ / 256, 256, 0, stream>>>(t0, sw1, sg0, sb0, t1, stats);
    k_ballq  <<<NQ / 32, 256, 0, stream>>>(bxyz, t1, sg1, sb1, stats, nxyz, idxb);
    k_gemm1  <<<NQ / 4, 256, 0, stream>>>(featT, bxyz, nxyz, idxb, w0p, y1, stats);
    k_gemm2  <<<NQ / 4, 256, 0, stream>>>(y1, w1p, mg0, mb0, mg1, stats, mv);
    k_final  <<<NQ / 8, 256, 0, stream>>>(mv, mg1, mb1, stats, out);
}